// Round 1
// baseline (2468.590 us; speedup 1.0000x reference)
//
#include <hip/hip_runtime.h>
#include <hip/hip_bf16.h>
#include <math.h>

// Problem constants (fixed by setup_inputs)
#define B  4
#define P  5000
#define NPT 100
#define CIN 8
#define F  64          // pointnet feature dim
#define NX 240
#define NY 240
#define C1 128         // conv1/conv2 channels
#define TILE 8         // pixels per block along iy

__device__ __forceinline__ float tanh_fast(float x) {
    float e = __expf(2.0f * x);
    return 1.0f - 2.0f / (e + 1.0f);
}

// ---------------------------------------------------------------------------
// PointNet: per pillar, thread-per-point. 128 threads (2 waves), 1 pillar/blk.
// acc[f] = b1[f] + sum_j tanh(b0[j]+x·w0[:,j]) * w1[j][f]; masked max over pts.
// ---------------------------------------------------------------------------
__global__ __launch_bounds__(128) void pn_kernel(
    const float* __restrict__ pillars,   // [B,P,N,8]
    const float* __restrict__ w0,        // [8,64]
    const float* __restrict__ b0,        // [64]
    const float* __restrict__ w1,        // [64,64]
    const float* __restrict__ b1,        // [64]
    float* __restrict__ pmax)            // [B*P,64]
{
    int bp = blockIdx.x;
    int n  = threadIdx.x;
    __shared__ float smax[2][F];

    bool live = (n < NPT);
    const float* xp = pillars + ((size_t)bp * NPT + (live ? n : 0)) * CIN;
    float4 a0 = *(const float4*)xp;
    float4 a1 = *(const float4*)(xp + 4);
    float x[8] = {a0.x, a0.y, a0.z, a0.w, a1.x, a1.y, a1.z, a1.w};

    float ss = 0.f;
#pragma unroll
    for (int c = 0; c < 8; c++) ss += x[c] * x[c];
    float valid = (ss < 1e12f) ? 1.0f : 0.0f;   // norm < 1e6

    float acc[F];
#pragma unroll
    for (int f = 0; f < F; f++) acc[f] = b1[f];

    for (int j = 0; j < F; j++) {
        float h = b0[j];
#pragma unroll
        for (int c = 0; c < 8; c++) h += x[c] * w0[c * F + j];
        h = tanh_fast(h);
        const float* w1r = w1 + j * F;
#pragma unroll
        for (int f = 0; f < F; f++) acc[f] += h * w1r[f];
    }

    int wv = n >> 6, lane = n & 63;
#pragma unroll
    for (int f = 0; f < F; f++) {
        float v = live ? acc[f] * valid : -INFINITY;
#pragma unroll
        for (int off = 32; off > 0; off >>= 1)
            v = fmaxf(v, __shfl_xor(v, off, 64));
        if (lane == 0) smax[wv][f] = v;
    }
    __syncthreads();
    if (n < F)
        pmax[(size_t)bp * F + n] = fmaxf(smax[0][n], smax[1][n]);
}

// ---------------------------------------------------------------------------
// Scatter with numpy last-write-wins: pass 1 atomicMax(p), pass 2 write winner.
// ---------------------------------------------------------------------------
__global__ __launch_bounds__(256) void winner_kernel(
    const int* __restrict__ idxs, int* __restrict__ winner)
{
    int i = blockIdx.x * 256 + threadIdx.x;
    if (i >= B * P) return;
    int ix = idxs[i * 2], iy = idxs[i * 2 + 1];
    int b = i / P, p = i % P;
    atomicMax(&winner[(b * NX + ix) * NY + iy], p);
}

__global__ __launch_bounds__(64) void scatter_kernel(
    const int* __restrict__ idxs, const int* __restrict__ winner,
    const float* __restrict__ pmax, float* __restrict__ img)
{
    int bp = blockIdx.x;
    int f = threadIdx.x;
    int ix = idxs[bp * 2], iy = idxs[bp * 2 + 1];
    int b = bp / P, p = bp % P;
    int cell = (b * NX + ix) * NY + iy;
    if (winner[cell] == p)
        img[(size_t)cell * F + f] = pmax[(size_t)bp * F + f];
}

// ---------------------------------------------------------------------------
// Conv1: 3x3, 64 -> 128, SAME, tanh. Thread = co, block = 8 iy-pixels.
// ---------------------------------------------------------------------------
__global__ __launch_bounds__(128) void conv1_kernel(
    const float* __restrict__ img,   // [B,240,240,64]
    const float* __restrict__ w,     // [3,3,64,128]
    const float* __restrict__ bias,  // [128]
    float* __restrict__ out)         // [B,240,240,128]
{
    __shared__ float sP[3 * 10 * F];   // 1920 floats
    int co  = threadIdx.x;
    int iy0 = blockIdx.x * TILE;
    int ix  = blockIdx.y;
    int b   = blockIdx.z;

    for (int t = threadIdx.x; t < 3 * 10 * (F / 4); t += 128) {
        int c4 = t & 15;
        int dy = (t >> 4) % 10;
        int dx = t / 160;
        int gx = ix + dx - 1, gy = iy0 + dy - 1;
        float4 v = make_float4(0.f, 0.f, 0.f, 0.f);
        if (gx >= 0 && gx < NX && gy >= 0 && gy < NY)
            v = *(const float4*)&img[(((size_t)b * NX + gx) * NY + gy) * F + c4 * 4];
        *(float4*)&sP[t * 4] = v;
    }
    __syncthreads();

    float acc[TILE];
#pragma unroll
    for (int p = 0; p < TILE; p++) acc[p] = bias[co];

    for (int kh = 0; kh < 3; kh++) {
        for (int c4 = 0; c4 < F / 4; c4++) {
            float4 v[10];
#pragma unroll
            for (int dy = 0; dy < 10; dy++)
                v[dy] = *(const float4*)&sP[((kh * 10 + dy) * 16 + c4) * 4];
#pragma unroll
            for (int kw = 0; kw < 3; kw++) {
#pragma unroll
                for (int cc = 0; cc < 4; cc++) {
                    float wv = w[(((kh * 3 + kw) * F) + c4 * 4 + cc) * C1 + co];
#pragma unroll
                    for (int p = 0; p < TILE; p++) {
                        const float* vp = (const float*)&v[kw + p];
                        acc[p] += vp[cc] * wv;
                    }
                }
            }
        }
    }

    size_t base = (((size_t)b * NX + ix) * NY + iy0) * C1 + co;
#pragma unroll
    for (int p = 0; p < TILE; p++)
        out[base + (size_t)p * C1] = tanh_fast(acc[p]);
}

// ---------------------------------------------------------------------------
// Conv2 (3x3, 128->128, tanh) fused with conv3 (1x1, 128->1) + relu.
// ---------------------------------------------------------------------------
__global__ __launch_bounds__(128) void conv23_kernel(
    const float* __restrict__ in1,   // [B,240,240,128]
    const float* __restrict__ w,     // [3,3,128,128]
    const float* __restrict__ bias,  // [128]
    const float* __restrict__ w2,    // [128]
    const float* __restrict__ b2,    // [1]
    float* __restrict__ out)         // [B,240,240]
{
    __shared__ float sP[3 * 10 * C1];   // 3840 floats = 15.36 KB
    __shared__ float sRed[2][TILE];
    int co  = threadIdx.x;
    int iy0 = blockIdx.x * TILE;
    int ix  = blockIdx.y;
    int b   = blockIdx.z;

    for (int t = threadIdx.x; t < 3 * 10 * (C1 / 4); t += 128) {
        int c4 = t & 31;
        int dy = (t >> 5) % 10;
        int dx = t / 320;
        int gx = ix + dx - 1, gy = iy0 + dy - 1;
        float4 v = make_float4(0.f, 0.f, 0.f, 0.f);
        if (gx >= 0 && gx < NX && gy >= 0 && gy < NY)
            v = *(const float4*)&in1[(((size_t)b * NX + gx) * NY + gy) * C1 + c4 * 4];
        *(float4*)&sP[t * 4] = v;
    }
    __syncthreads();

    float acc[TILE];
#pragma unroll
    for (int p = 0; p < TILE; p++) acc[p] = bias[co];

    for (int kh = 0; kh < 3; kh++) {
        for (int c4 = 0; c4 < C1 / 4; c4++) {
            float4 v[10];
#pragma unroll
            for (int dy = 0; dy < 10; dy++)
                v[dy] = *(const float4*)&sP[((kh * 10 + dy) * 32 + c4) * 4];
#pragma unroll
            for (int kw = 0; kw < 3; kw++) {
#pragma unroll
                for (int cc = 0; cc < 4; cc++) {
                    float wv = w[(((kh * 3 + kw) * C1) + c4 * 4 + cc) * C1 + co];
#pragma unroll
                    for (int p = 0; p < TILE; p++) {
                        const float* vp = (const float*)&v[kw + p];
                        acc[p] += vp[cc] * wv;
                    }
                }
            }
        }
    }

    // tanh, then 1x1 conv: out[p] = relu(b2 + sum_co tanh(acc)[co] * w2[co])
    float wv2 = w2[co];
    float pv[TILE];
#pragma unroll
    for (int p = 0; p < TILE; p++) pv[p] = tanh_fast(acc[p]) * wv2;

    int wv = threadIdx.x >> 6, lane = threadIdx.x & 63;
#pragma unroll
    for (int p = 0; p < TILE; p++) {
#pragma unroll
        for (int off = 32; off > 0; off >>= 1)
            pv[p] += __shfl_xor(pv[p], off, 64);
    }
    if (lane == 0) {
#pragma unroll
        for (int p = 0; p < TILE; p++) sRed[wv][p] = pv[p];
    }
    __syncthreads();
    if (threadIdx.x < TILE) {
        float r = sRed[0][threadIdx.x] + sRed[1][threadIdx.x] + b2[0];
        out[((size_t)b * NX + ix) * NY + iy0 + threadIdx.x] = fmaxf(r, 0.f);
    }
}

// ---------------------------------------------------------------------------
extern "C" void kernel_launch(void* const* d_in, const int* in_sizes, int n_in,
                              void* d_out, int out_size, void* d_ws, size_t ws_size,
                              hipStream_t stream) {
    const float* pillars = (const float*)d_in[0];
    const int*   idxs    = (const int*)d_in[1];
    // d_in[2], d_in[3] = nx, ny scalars (fixed at 240)
    const float* pn_w0   = (const float*)d_in[4];
    const float* pn_b0   = (const float*)d_in[5];
    const float* pn_w1   = (const float*)d_in[6];
    const float* pn_b1   = (const float*)d_in[7];
    const float* cw0     = (const float*)d_in[8];
    const float* cb0     = (const float*)d_in[9];
    const float* cw1     = (const float*)d_in[10];
    const float* cb1     = (const float*)d_in[11];
    const float* cw2     = (const float*)d_in[12];
    const float* cb2     = (const float*)d_in[13];
    float* out = (float*)d_out;

    // workspace layout
    char* ws = (char*)d_ws;
    const size_t IMG_BYTES  = (size_t)B * NX * NY * F * 4;    // 58,982,400
    const size_t OUT1_BYTES = (size_t)B * NX * NY * C1 * 4;   // 117,964,800
    const size_t WIN_BYTES  = (size_t)B * NX * NY * 4;        //     921,600
    float* img    = (float*)ws;
    float* out1   = (float*)(ws + IMG_BYTES);
    int*   winner = (int*)(ws + IMG_BYTES + OUT1_BYTES);
    float* pmax   = (float*)(ws + IMG_BYTES + OUT1_BYTES + WIN_BYTES);

    hipMemsetAsync(img, 0, IMG_BYTES, stream);
    hipMemsetAsync(winner, 0xFF, WIN_BYTES, stream);   // -1

    pn_kernel<<<B * P, 128, 0, stream>>>(pillars, pn_w0, pn_b0, pn_w1, pn_b1, pmax);
    winner_kernel<<<(B * P + 255) / 256, 256, 0, stream>>>(idxs, winner);
    scatter_kernel<<<B * P, 64, 0, stream>>>(idxs, winner, pmax, img);
    conv1_kernel<<<dim3(NY / TILE, NX, B), 128, 0, stream>>>(img, cw0, cb0, out1);
    conv23_kernel<<<dim3(NY / TILE, NX, B), 128, 0, stream>>>(out1, cw1, cb1, cw2, cb2, out);
}

// Round 2
// 743.875 us; speedup vs baseline: 3.3186x; 3.3186x over previous
//
#include <hip/hip_runtime.h>
#include <hip/hip_bf16.h>
#include <math.h>

// Problem constants (fixed by setup_inputs)
#define B  4
#define P  5000
#define NPT 100
#define CIN_PN 8
#define F  64          // pointnet feature dim
#define NX 240
#define NY 240
#define C1 128         // conv1/conv2 out channels

typedef __attribute__((ext_vector_type(8)))  short short8;   // 8 bf16
typedef __attribute__((ext_vector_type(16))) float f32x16;

__device__ __forceinline__ float tanh_fast(float x) {
    float e = __expf(2.0f * x);
    return 1.0f - 2.0f / (e + 1.0f);
}

// ---------------------------------------------------------------------------
// PointNet: per pillar, thread-per-point (fp32, unchanged from R1).
// ---------------------------------------------------------------------------
__global__ __launch_bounds__(128) void pn_kernel(
    const float* __restrict__ pillars,   // [B,P,N,8]
    const float* __restrict__ w0,        // [8,64]
    const float* __restrict__ b0,        // [64]
    const float* __restrict__ w1,        // [64,64]
    const float* __restrict__ b1,        // [64]
    float* __restrict__ pmax)            // [B*P,64]
{
    int bp = blockIdx.x;
    int n  = threadIdx.x;
    __shared__ float smax[2][F];

    bool live = (n < NPT);
    const float* xp = pillars + ((size_t)bp * NPT + (live ? n : 0)) * CIN_PN;
    float4 a0 = *(const float4*)xp;
    float4 a1 = *(const float4*)(xp + 4);
    float x[8] = {a0.x, a0.y, a0.z, a0.w, a1.x, a1.y, a1.z, a1.w};

    float ss = 0.f;
#pragma unroll
    for (int c = 0; c < 8; c++) ss += x[c] * x[c];
    float valid = (ss < 1e12f) ? 1.0f : 0.0f;   // norm < 1e6

    float acc[F];
#pragma unroll
    for (int f = 0; f < F; f++) acc[f] = b1[f];

    for (int j = 0; j < F; j++) {
        float h = b0[j];
#pragma unroll
        for (int c = 0; c < 8; c++) h += x[c] * w0[c * F + j];
        h = tanh_fast(h);
        const float* w1r = w1 + j * F;
#pragma unroll
        for (int f = 0; f < F; f++) acc[f] += h * w1r[f];
    }

    int wv = n >> 6, lane = n & 63;
#pragma unroll
    for (int f = 0; f < F; f++) {
        float v = live ? acc[f] * valid : -INFINITY;
#pragma unroll
        for (int off = 32; off > 0; off >>= 1)
            v = fmaxf(v, __shfl_xor(v, off, 64));
        if (lane == 0) smax[wv][f] = v;
    }
    __syncthreads();
    if (n < F)
        pmax[(size_t)bp * F + n] = fmaxf(smax[0][n], smax[1][n]);
}

// ---------------------------------------------------------------------------
// Scatter with numpy last-write-wins: pass 1 atomicMax(p), pass 2 write winner.
// img is bf16 now (feeds MFMA conv1).
// ---------------------------------------------------------------------------
__global__ __launch_bounds__(256) void winner_kernel(
    const int* __restrict__ idxs, int* __restrict__ winner)
{
    int i = blockIdx.x * 256 + threadIdx.x;
    if (i >= B * P) return;
    int ix = idxs[i * 2], iy = idxs[i * 2 + 1];
    int b = i / P, p = i % P;
    atomicMax(&winner[(b * NX + ix) * NY + iy], p);
}

__global__ __launch_bounds__(64) void scatter_kernel(
    const int* __restrict__ idxs, const int* __restrict__ winner,
    const float* __restrict__ pmax, __hip_bfloat16* __restrict__ img)
{
    int bp = blockIdx.x;
    int f = threadIdx.x;
    int ix = idxs[bp * 2], iy = idxs[bp * 2 + 1];
    int b = bp / P, p = bp % P;
    int cell = (b * NX + ix) * NY + iy;
    if (winner[cell] == p)
        img[(size_t)cell * F + f] = __float2bfloat16(pmax[(size_t)bp * F + f]);
}

// ---------------------------------------------------------------------------
// Weight convert+transpose: w [3,3,cin,128] f32 -> wt [9][128][cin] bf16
// ---------------------------------------------------------------------------
__global__ __launch_bounds__(256) void cvt_w_kernel(
    const float* __restrict__ w, __hip_bfloat16* __restrict__ wt, int cin)
{
    int idx = blockIdx.x * 256 + threadIdx.x;
    int total = 9 * cin * 128;
    if (idx >= total) return;
    int co = idx % 128;
    int rest = idx / 128;
    int ci = rest % cin;
    int t  = rest / cin;
    wt[((size_t)(t * 128 + co)) * cin + ci] = __float2bfloat16(w[idx]);
}

// ---------------------------------------------------------------------------
// MFMA implicit-GEMM 3x3 conv, SAME, Cout=128.
// Block: 64 pixels (one x-row, y0..y0+63, masked at y>=240) x 128 cout.
// 4 waves split cout (32 each); wave = 2 M-tiles(32px) x 1 N-tile(32co).
// K-loop: 9 taps x CIN/16 chunks with v_mfma_f32_32x32x16_bf16.
// FUSE=false: out_bf = tanh(conv+bias) bf16 [B,240,240,128]
// FUSE=true : out_f  = relu(sum_co tanh(conv+bias)*w2[co] + b2) fp32 [B,240,240]
// ---------------------------------------------------------------------------
template<int CIN, bool FUSE>
__global__ __launch_bounds__(256) void conv_mfma(
    const __hip_bfloat16* __restrict__ in,    // [B,240,240,CIN] bf16
    const __hip_bfloat16* __restrict__ wt,    // [9][128][CIN] bf16
    const float* __restrict__ bias,           // [128]
    const float* __restrict__ w2,             // [128] (FUSE)
    const float* __restrict__ b2,             // [1]   (FUSE)
    __hip_bfloat16* __restrict__ out_bf,
    float* __restrict__ out_f)
{
    constexpr int CPAD = CIN + 8;             // +16B pad: 2-way bank alias (free)
    __shared__ __hip_bfloat16 sP[3 * 66 * CPAD];
    __shared__ float sred[4][64];

    int tid  = threadIdx.x;
    int wave = tid >> 6;
    int lane = tid & 63;
    int m = lane & 31;            // M (A) / N (B) index within tile
    int g = lane >> 5;            // k-group
    int y0 = blockIdx.x * 64;
    int ix = blockIdx.y;
    int b  = blockIdx.z;

    // ---- stage input patch [3][66][CIN] -> LDS (zero-padded at borders) ----
    constexpr int NC8 = CIN / 8;
    for (int t = tid; t < 3 * 66 * NC8; t += 256) {
        int c8  = t & (NC8 - 1);
        int row = t / NC8;
        int dy  = row % 66;
        int kh  = row / 66;
        int gx = ix + kh - 1, gy = y0 + dy - 1;
        float4 v = make_float4(0.f, 0.f, 0.f, 0.f);
        if (gx >= 0 && gx < NX && gy >= 0 && gy < NY)
            v = *(const float4*)&in[(((size_t)b * NX + gx) * NY + gy) * CIN + c8 * 8];
        *(float4*)&sP[row * CPAD + c8 * 8] = v;
    }
    __syncthreads();

    // ---- K-loop ----
    f32x16 acc0 = {0,0,0,0,0,0,0,0,0,0,0,0,0,0,0,0};
    f32x16 acc1 = {0,0,0,0,0,0,0,0,0,0,0,0,0,0,0,0};
    const short* sPs = (const short*)sP;
    const short* wts = (const short*)wt;
    int cobase = wave * 32 + m;

#pragma unroll
    for (int kh = 0; kh < 3; kh++) {
#pragma unroll
        for (int kw = 0; kw < 3; kw++) {
            const short* wrow = wts + ((size_t)((kh * 3 + kw) * 128 + cobase)) * CIN + g * 8;
            int prow = (kh * 66 + kw + m) * CPAD + g * 8;
#pragma unroll
            for (int c0 = 0; c0 < CIN; c0 += 16) {
                short8 bfrag = *(const short8*)(wrow + c0);
                short8 a0 = *(const short8*)(sPs + prow + c0);
                short8 a1 = *(const short8*)(sPs + prow + 32 * CPAD + c0);
                acc0 = __builtin_amdgcn_mfma_f32_32x32x16_bf16(a0, bfrag, acc0, 0, 0, 0);
                acc1 = __builtin_amdgcn_mfma_f32_32x32x16_bf16(a1, bfrag, acc1, 0, 0, 0);
            }
        }
    }

    // ---- epilogue ----
    float bv = bias[cobase];
    if (!FUSE) {
        size_t base = (((size_t)b * NX + ix) * NY);
#pragma unroll
        for (int half = 0; half < 2; half++) {
#pragma unroll
            for (int r = 0; r < 16; r++) {
                float a = (half == 0) ? acc0[r] : acc1[r];
                int row = (r & 3) + 8 * (r >> 2) + 4 * g;
                int y = y0 + half * 32 + row;
                if (y < NY)
                    out_bf[(base + y) * C1 + cobase] = __float2bfloat16(tanh_fast(a + bv));
            }
        }
    } else {
        float wv2 = w2[cobase];
#pragma unroll
        for (int half = 0; half < 2; half++) {
#pragma unroll
            for (int r = 0; r < 16; r++) {
                float a = (half == 0) ? acc0[r] : acc1[r];
                float v = tanh_fast(a + bv) * wv2;
                v += __shfl_xor(v, 1, 64);
                v += __shfl_xor(v, 2, 64);
                v += __shfl_xor(v, 4, 64);
                v += __shfl_xor(v, 8, 64);
                v += __shfl_xor(v, 16, 64);
                if (m == 0) {
                    int row = (r & 3) + 8 * (r >> 2) + 4 * g;
                    sred[wave][half * 32 + row] = v;
                }
            }
        }
        __syncthreads();
        if (tid < 64) {
            int y = y0 + tid;
            if (y < NY) {
                float r = sred[0][tid] + sred[1][tid] + sred[2][tid] + sred[3][tid] + b2[0];
                out_f[((size_t)b * NX + ix) * NY + y] = fmaxf(r, 0.f);
            }
        }
    }
}

// ---------------------------------------------------------------------------
extern "C" void kernel_launch(void* const* d_in, const int* in_sizes, int n_in,
                              void* d_out, int out_size, void* d_ws, size_t ws_size,
                              hipStream_t stream) {
    const float* pillars = (const float*)d_in[0];
    const int*   idxs    = (const int*)d_in[1];
    const float* pn_w0   = (const float*)d_in[4];
    const float* pn_b0   = (const float*)d_in[5];
    const float* pn_w1   = (const float*)d_in[6];
    const float* pn_b1   = (const float*)d_in[7];
    const float* cw0     = (const float*)d_in[8];
    const float* cb0     = (const float*)d_in[9];
    const float* cw1     = (const float*)d_in[10];
    const float* cb1     = (const float*)d_in[11];
    const float* cw2     = (const float*)d_in[12];
    const float* cb2     = (const float*)d_in[13];
    float* out = (float*)d_out;

    // workspace layout
    char* ws = (char*)d_ws;
    const size_t IMG_BYTES  = (size_t)B * NX * NY * F * 2;    // 29,491,200 bf16
    const size_t OUT1_BYTES = (size_t)B * NX * NY * C1 * 2;   // 58,982,400 bf16
    const size_t WIN_BYTES  = (size_t)B * NX * NY * 4;        //    921,600
    const size_t PMAX_BYTES = (size_t)B * P * F * 4;          //  5,120,000
    const size_t WT1_BYTES  = (size_t)9 * C1 * F * 2;         //    147,456
    __hip_bfloat16* img  = (__hip_bfloat16*)ws;
    __hip_bfloat16* out1 = (__hip_bfloat16*)(ws + IMG_BYTES);
    int*   winner = (int*)(ws + IMG_BYTES + OUT1_BYTES);
    float* pmax   = (float*)(ws + IMG_BYTES + OUT1_BYTES + WIN_BYTES);
    __hip_bfloat16* wt1 = (__hip_bfloat16*)(ws + IMG_BYTES + OUT1_BYTES + WIN_BYTES + PMAX_BYTES);
    __hip_bfloat16* wt2 = (__hip_bfloat16*)(ws + IMG_BYTES + OUT1_BYTES + WIN_BYTES + PMAX_BYTES + WT1_BYTES);

    hipMemsetAsync(img, 0, IMG_BYTES, stream);
    hipMemsetAsync(winner, 0xFF, WIN_BYTES, stream);   // -1

    cvt_w_kernel<<<(9 * F * C1 + 255) / 256, 256, 0, stream>>>(cw0, wt1, F);
    cvt_w_kernel<<<(9 * C1 * C1 + 255) / 256, 256, 0, stream>>>(cw1, wt2, C1);

    pn_kernel<<<B * P, 128, 0, stream>>>(pillars, pn_w0, pn_b0, pn_w1, pn_b1, pmax);
    winner_kernel<<<(B * P + 255) / 256, 256, 0, stream>>>(idxs, winner);
    scatter_kernel<<<B * P, 64, 0, stream>>>(idxs, winner, pmax, img);

    conv_mfma<F, false><<<dim3(4, NX, B), 256, 0, stream>>>(
        img, wt1, cb0, nullptr, nullptr, out1, nullptr);
    conv_mfma<C1, true><<<dim3(4, NX, B), 256, 0, stream>>>(
        out1, wt2, cb1, cw2, cb2, nullptr, out);
}

// Round 3
// 567.396 us; speedup vs baseline: 4.3507x; 1.3110x over previous
//
#include <hip/hip_runtime.h>
#include <hip/hip_bf16.h>
#include <math.h>

// Problem constants (fixed by setup_inputs)
#define B  4
#define P  5000
#define NPT 100
#define F  64          // pointnet feature dim
#define NX 240
#define NY 240
#define C1 128         // conv1/conv2 out channels

typedef __attribute__((ext_vector_type(8)))  short short8;   // 8 bf16
typedef __attribute__((ext_vector_type(16))) float f32x16;

__device__ __forceinline__ float tanh_fast(float x) {
    float e = __expf(2.0f * x);
    return 1.0f - 2.0f / (e + 1.0f);
}
__device__ __forceinline__ short bf16_bits(float f) {
    return (short)(__bfloat16_as_ushort(__float2bfloat16(f)));
}

// ---------------------------------------------------------------------------
// PointNet with MFMA layer 2.
// Block = 1 pillar (128 threads = 2 waves; points 100..127 are phantoms).
// Phase 1 (VALU fp32): h = tanh(x@w0+b0), written bf16 to LDS rows.
// Phase 2 (MFMA): feat = hA[128x64] @ w1t^T via 32x32x16 bf16, fused
//                 +b1, x valid, masked max over points -> pmax[bp][64].
// ---------------------------------------------------------------------------
__global__ __launch_bounds__(128) void pn_mfma_kernel(
    const float* __restrict__ pillars,    // [B,P,N,8]
    const float* __restrict__ w0,         // [8,64]
    const float* __restrict__ b0,         // [64]
    const __hip_bfloat16* __restrict__ w1t, // [64n][64k] bf16 (transposed w1)
    const float* __restrict__ b1,         // [64]
    float* __restrict__ pmax)             // [B*P,64]
{
    constexpr int HS = F + 8;             // 72 shorts = 144B = 9 granules
    __shared__ short hA[128 * HS];
    __shared__ float vmask[128];
    __shared__ float red[2][F];

    int bp = blockIdx.x;
    int n  = threadIdx.x;
    bool live = (n < NPT);

    const float* xp = pillars + ((size_t)bp * NPT + (live ? n : 0)) * 8;
    float4 q0 = *(const float4*)xp;
    float4 q1 = *(const float4*)(xp + 4);
    float x[8] = {q0.x, q0.y, q0.z, q0.w, q1.x, q1.y, q1.z, q1.w};

    float ss = 0.f;
#pragma unroll
    for (int c = 0; c < 8; c++) ss += x[c] * x[c];
    vmask[n] = live ? ((ss < 1e12f) ? 1.0f : 0.0f) : -1.0f;

    // ---- phase 1: layer 1, 8 features at a time ----
    for (int j0 = 0; j0 < F; j0 += 8) {
        short8 hv;
#pragma unroll
        for (int jj = 0; jj < 8; jj++) {
            float h = b0[j0 + jj];
#pragma unroll
            for (int c = 0; c < 8; c++) h += x[c] * w0[c * F + j0 + jj];
            hv[jj] = bf16_bits(tanh_fast(h));
        }
        *(short8*)&hA[n * HS + j0] = hv;
    }
    __syncthreads();

    // ---- phase 2: MFMA ----
    int wave = n >> 6, lane = n & 63;
    int mr = lane & 31;       // A row / C col index within tile
    int g  = lane >> 5;       // k-half

    short8 bfrag[2][4];
#pragma unroll
    for (int nt = 0; nt < 2; nt++)
#pragma unroll
        for (int c0 = 0; c0 < 4; c0++)
            bfrag[nt][c0] = *(const short8*)((const short*)w1t +
                                (nt * 32 + mr) * F + c0 * 16 + g * 8);

    f32x16 acc00 = {0,0,0,0,0,0,0,0,0,0,0,0,0,0,0,0};
    f32x16 acc01 = acc00, acc10 = acc00, acc11 = acc00;

    const short* arow = &hA[(wave * 64 + mr) * HS + g * 8];
#pragma unroll
    for (int c0 = 0; c0 < 4; c0++) {
        short8 af0 = *(const short8*)(arow + c0 * 16);
        short8 af1 = *(const short8*)(arow + 32 * HS + c0 * 16);
        acc00 = __builtin_amdgcn_mfma_f32_32x32x16_bf16(af0, bfrag[0][c0], acc00, 0, 0, 0);
        acc01 = __builtin_amdgcn_mfma_f32_32x32x16_bf16(af0, bfrag[1][c0], acc01, 0, 0, 0);
        acc10 = __builtin_amdgcn_mfma_f32_32x32x16_bf16(af1, bfrag[0][c0], acc10, 0, 0, 0);
        acc11 = __builtin_amdgcn_mfma_f32_32x32x16_bf16(af1, bfrag[1][c0], acc11, 0, 0, 0);
    }

    // ---- epilogue: +b1, mask, max over points ----
    float bv0 = b1[mr];
    float bv1 = b1[32 + mr];
    float mx0 = -INFINITY, mx1 = -INFINITY;
#pragma unroll
    for (int mt = 0; mt < 2; mt++) {
#pragma unroll
        for (int r = 0; r < 16; r++) {
            int row = (r & 3) + 8 * (r >> 2) + 4 * g;
            int p = wave * 64 + mt * 32 + row;
            float vm = vmask[p];
            float a0 = (mt == 0) ? acc00[r] : acc10[r];
            float a1 = (mt == 0) ? acc01[r] : acc11[r];
            float v0 = (vm < 0.f) ? -INFINITY : (a0 + bv0) * vm;
            float v1 = (vm < 0.f) ? -INFINITY : (a1 + bv1) * vm;
            mx0 = fmaxf(mx0, v0);
            mx1 = fmaxf(mx1, v1);
        }
    }
    mx0 = fmaxf(mx0, __shfl_xor(mx0, 32, 64));
    mx1 = fmaxf(mx1, __shfl_xor(mx1, 32, 64));
    if (lane < 32) { red[wave][mr] = mx0; red[wave][32 + mr] = mx1; }
    __syncthreads();
    if (n < F)
        pmax[(size_t)bp * F + n] = fmaxf(red[0][n], red[1][n]);
}

// ---------------------------------------------------------------------------
// Scatter with numpy last-write-wins: pass 1 atomicMax(p), pass 2 write winner.
// ---------------------------------------------------------------------------
__global__ __launch_bounds__(256) void winner_kernel(
    const int* __restrict__ idxs, int* __restrict__ winner)
{
    int i = blockIdx.x * 256 + threadIdx.x;
    if (i >= B * P) return;
    int ix = idxs[i * 2], iy = idxs[i * 2 + 1];
    int b = i / P, p = i % P;
    atomicMax(&winner[(b * NX + ix) * NY + iy], p);
}

__global__ __launch_bounds__(64) void scatter_kernel(
    const int* __restrict__ idxs, const int* __restrict__ winner,
    const float* __restrict__ pmax, __hip_bfloat16* __restrict__ img)
{
    int bp = blockIdx.x;
    int f = threadIdx.x;
    int ix = idxs[bp * 2], iy = idxs[bp * 2 + 1];
    int b = bp / P, p = bp % P;
    int cell = (b * NX + ix) * NY + iy;
    if (winner[cell] == p)
        img[(size_t)cell * F + f] = __float2bfloat16(pmax[(size_t)bp * F + f]);
}

// ---------------------------------------------------------------------------
// Weight converts
// ---------------------------------------------------------------------------
__global__ __launch_bounds__(256) void cvt_w_kernel(
    const float* __restrict__ w, __hip_bfloat16* __restrict__ wt, int cin)
{
    int idx = blockIdx.x * 256 + threadIdx.x;
    int total = 9 * cin * 128;
    if (idx >= total) return;
    int co = idx % 128;
    int rest = idx / 128;
    int ci = rest % cin;
    int t  = rest / cin;
    wt[((size_t)(t * 128 + co)) * cin + ci] = __float2bfloat16(w[idx]);
}

__global__ __launch_bounds__(256) void cvt_w1_kernel(
    const float* __restrict__ w1, __hip_bfloat16* __restrict__ w1t)
{
    int idx = blockIdx.x * 256 + threadIdx.x;
    if (idx >= F * F) return;
    int k = idx >> 6, nn = idx & 63;
    w1t[nn * F + k] = __float2bfloat16(w1[idx]);
}

// ---------------------------------------------------------------------------
// MFMA implicit-GEMM 3x3 conv, SAME, Cout=128 (unchanged from R2).
// ---------------------------------------------------------------------------
template<int CIN, bool FUSE>
__global__ __launch_bounds__(256) void conv_mfma(
    const __hip_bfloat16* __restrict__ in,
    const __hip_bfloat16* __restrict__ wt,    // [9][128][CIN] bf16
    const float* __restrict__ bias,
    const float* __restrict__ w2,
    const float* __restrict__ b2,
    __hip_bfloat16* __restrict__ out_bf,
    float* __restrict__ out_f)
{
    constexpr int CPAD = CIN + 8;
    __shared__ __hip_bfloat16 sP[3 * 66 * CPAD];
    __shared__ float sred[4][64];

    int tid  = threadIdx.x;
    int wave = tid >> 6;
    int lane = tid & 63;
    int m = lane & 31;
    int g = lane >> 5;
    int y0 = blockIdx.x * 64;
    int ix = blockIdx.y;
    int b  = blockIdx.z;

    constexpr int NC8 = CIN / 8;
    for (int t = tid; t < 3 * 66 * NC8; t += 256) {
        int c8  = t & (NC8 - 1);
        int row = t / NC8;
        int dy  = row % 66;
        int kh  = row / 66;
        int gx = ix + kh - 1, gy = y0 + dy - 1;
        float4 v = make_float4(0.f, 0.f, 0.f, 0.f);
        if (gx >= 0 && gx < NX && gy >= 0 && gy < NY)
            v = *(const float4*)&in[(((size_t)b * NX + gx) * NY + gy) * CIN + c8 * 8];
        *(float4*)&sP[row * CPAD + c8 * 8] = v;
    }
    __syncthreads();

    f32x16 acc0 = {0,0,0,0,0,0,0,0,0,0,0,0,0,0,0,0};
    f32x16 acc1 = acc0;
    const short* sPs = (const short*)sP;
    const short* wts = (const short*)wt;
    int cobase = wave * 32 + m;

#pragma unroll
    for (int kh = 0; kh < 3; kh++) {
#pragma unroll
        for (int kw = 0; kw < 3; kw++) {
            const short* wrow = wts + ((size_t)((kh * 3 + kw) * 128 + cobase)) * CIN + g * 8;
            int prow = (kh * 66 + kw + m) * CPAD + g * 8;
#pragma unroll
            for (int c0 = 0; c0 < CIN; c0 += 16) {
                short8 bfrag = *(const short8*)(wrow + c0);
                short8 a0 = *(const short8*)(sPs + prow + c0);
                short8 a1 = *(const short8*)(sPs + prow + 32 * CPAD + c0);
                acc0 = __builtin_amdgcn_mfma_f32_32x32x16_bf16(a0, bfrag, acc0, 0, 0, 0);
                acc1 = __builtin_amdgcn_mfma_f32_32x32x16_bf16(a1, bfrag, acc1, 0, 0, 0);
            }
        }
    }

    float bv = bias[cobase];
    if (!FUSE) {
        size_t base = (((size_t)b * NX + ix) * NY);
#pragma unroll
        for (int half = 0; half < 2; half++) {
#pragma unroll
            for (int r = 0; r < 16; r++) {
                float a = (half == 0) ? acc0[r] : acc1[r];
                int row = (r & 3) + 8 * (r >> 2) + 4 * g;
                int y = y0 + half * 32 + row;
                if (y < NY)
                    out_bf[(base + y) * C1 + cobase] = __float2bfloat16(tanh_fast(a + bv));
            }
        }
    } else {
        float wv2 = w2[cobase];
#pragma unroll
        for (int half = 0; half < 2; half++) {
#pragma unroll
            for (int r = 0; r < 16; r++) {
                float a = (half == 0) ? acc0[r] : acc1[r];
                float v = tanh_fast(a + bv) * wv2;
                v += __shfl_xor(v, 1, 64);
                v += __shfl_xor(v, 2, 64);
                v += __shfl_xor(v, 4, 64);
                v += __shfl_xor(v, 8, 64);
                v += __shfl_xor(v, 16, 64);
                if (m == 0) {
                    int row = (r & 3) + 8 * (r >> 2) + 4 * g;
                    sred[wave][half * 32 + row] = v;
                }
            }
        }
        __syncthreads();
        if (tid < 64) {
            int y = y0 + tid;
            if (y < NY) {
                float r = sred[0][tid] + sred[1][tid] + sred[2][tid] + sred[3][tid] + b2[0];
                out_f[((size_t)b * NX + ix) * NY + y] = fmaxf(r, 0.f);
            }
        }
    }
}

// ---------------------------------------------------------------------------
extern "C" void kernel_launch(void* const* d_in, const int* in_sizes, int n_in,
                              void* d_out, int out_size, void* d_ws, size_t ws_size,
                              hipStream_t stream) {
    const float* pillars = (const float*)d_in[0];
    const int*   idxs    = (const int*)d_in[1];
    const float* pn_w0   = (const float*)d_in[4];
    const float* pn_b0   = (const float*)d_in[5];
    const float* pn_w1   = (const float*)d_in[6];
    const float* pn_b1   = (const float*)d_in[7];
    const float* cw0     = (const float*)d_in[8];
    const float* cb0     = (const float*)d_in[9];
    const float* cw1     = (const float*)d_in[10];
    const float* cb1     = (const float*)d_in[11];
    const float* cw2     = (const float*)d_in[12];
    const float* cb2     = (const float*)d_in[13];
    float* out = (float*)d_out;

    // workspace layout
    char* ws = (char*)d_ws;
    const size_t IMG_BYTES  = (size_t)B * NX * NY * F * 2;    // bf16
    const size_t OUT1_BYTES = (size_t)B * NX * NY * C1 * 2;   // bf16
    const size_t WIN_BYTES  = (size_t)B * NX * NY * 4;
    const size_t PMAX_BYTES = (size_t)B * P * F * 4;
    const size_t WT1_BYTES  = (size_t)9 * C1 * F * 2;
    const size_t WT2_BYTES  = (size_t)9 * C1 * C1 * 2;
    __hip_bfloat16* img  = (__hip_bfloat16*)ws;
    __hip_bfloat16* out1 = (__hip_bfloat16*)(ws + IMG_BYTES);
    int*   winner = (int*)(ws + IMG_BYTES + OUT1_BYTES);
    float* pmax   = (float*)(ws + IMG_BYTES + OUT1_BYTES + WIN_BYTES);
    __hip_bfloat16* wt1 = (__hip_bfloat16*)(ws + IMG_BYTES + OUT1_BYTES + WIN_BYTES + PMAX_BYTES);
    __hip_bfloat16* wt2 = (__hip_bfloat16*)(ws + IMG_BYTES + OUT1_BYTES + WIN_BYTES + PMAX_BYTES + WT1_BYTES);
    __hip_bfloat16* w1t = (__hip_bfloat16*)(ws + IMG_BYTES + OUT1_BYTES + WIN_BYTES + PMAX_BYTES + WT1_BYTES + WT2_BYTES);

    hipMemsetAsync(img, 0, IMG_BYTES, stream);
    hipMemsetAsync(winner, 0xFF, WIN_BYTES, stream);   // -1

    cvt_w_kernel<<<(9 * F * C1 + 255) / 256, 256, 0, stream>>>(cw0, wt1, F);
    cvt_w_kernel<<<(9 * C1 * C1 + 255) / 256, 256, 0, stream>>>(cw1, wt2, C1);
    cvt_w1_kernel<<<(F * F + 255) / 256, 256, 0, stream>>>(pn_w1, w1t);

    pn_mfma_kernel<<<B * P, 128, 0, stream>>>(pillars, pn_w0, pn_b0, w1t, pn_b1, pmax);
    winner_kernel<<<(B * P + 255) / 256, 256, 0, stream>>>(idxs, winner);
    scatter_kernel<<<B * P, 64, 0, stream>>>(idxs, winner, pmax, img);

    conv_mfma<F, false><<<dim3(4, NX, B), 256, 0, stream>>>(
        img, wt1, cb0, nullptr, nullptr, out1, nullptr);
    conv_mfma<C1, true><<<dim3(4, NX, B), 256, 0, stream>>>(
        out1, wt2, cb1, cw2, cb2, nullptr, out);
}

// Round 4
// 557.274 us; speedup vs baseline: 4.4298x; 1.0182x over previous
//
#include <hip/hip_runtime.h>
#include <hip/hip_bf16.h>
#include <math.h>

// Problem constants (fixed by setup_inputs)
#define B  4
#define P  5000
#define NPT 100
#define F  64          // pointnet feature dim
#define NX 240
#define NY 240
#define C1 128         // conv1/conv2 out channels

typedef __attribute__((ext_vector_type(8)))  short short8;   // 8 bf16
typedef __attribute__((ext_vector_type(16))) float f32x16;

__device__ __forceinline__ float tanh_fast(float x) {
    float e = __expf(2.0f * x);
    return 1.0f - 2.0f / (e + 1.0f);
}
__device__ __forceinline__ short bf16_bits(float f) {
    return (short)(__bfloat16_as_ushort(__float2bfloat16(f)));
}

// ---------------------------------------------------------------------------
// PointNet with MFMA layer 2 (unchanged from R3).
// ---------------------------------------------------------------------------
__global__ __launch_bounds__(128) void pn_mfma_kernel(
    const float* __restrict__ pillars,    // [B,P,N,8]
    const float* __restrict__ w0,         // [8,64]
    const float* __restrict__ b0,         // [64]
    const __hip_bfloat16* __restrict__ w1t, // [64n][64k] bf16
    const float* __restrict__ b1,         // [64]
    float* __restrict__ pmax)             // [B*P,64]
{
    constexpr int HS = F + 8;             // 72 shorts
    __shared__ short hA[128 * HS];
    __shared__ float vmask[128];
    __shared__ float red[2][F];

    int bp = blockIdx.x;
    int n  = threadIdx.x;
    bool live = (n < NPT);

    const float* xp = pillars + ((size_t)bp * NPT + (live ? n : 0)) * 8;
    float4 q0 = *(const float4*)xp;
    float4 q1 = *(const float4*)(xp + 4);
    float x[8] = {q0.x, q0.y, q0.z, q0.w, q1.x, q1.y, q1.z, q1.w};

    float ss = 0.f;
#pragma unroll
    for (int c = 0; c < 8; c++) ss += x[c] * x[c];
    vmask[n] = live ? ((ss < 1e12f) ? 1.0f : 0.0f) : -1.0f;

    for (int j0 = 0; j0 < F; j0 += 8) {
        short8 hv;
#pragma unroll
        for (int jj = 0; jj < 8; jj++) {
            float h = b0[j0 + jj];
#pragma unroll
            for (int c = 0; c < 8; c++) h += x[c] * w0[c * F + j0 + jj];
            hv[jj] = bf16_bits(tanh_fast(h));
        }
        *(short8*)&hA[n * HS + j0] = hv;
    }
    __syncthreads();

    int wave = n >> 6, lane = n & 63;
    int mr = lane & 31;
    int g  = lane >> 5;

    short8 bfrag[2][4];
#pragma unroll
    for (int nt = 0; nt < 2; nt++)
#pragma unroll
        for (int c0 = 0; c0 < 4; c0++)
            bfrag[nt][c0] = *(const short8*)((const short*)w1t +
                                (nt * 32 + mr) * F + c0 * 16 + g * 8);

    f32x16 acc00 = {0,0,0,0,0,0,0,0,0,0,0,0,0,0,0,0};
    f32x16 acc01 = acc00, acc10 = acc00, acc11 = acc00;

    const short* arow = &hA[(wave * 64 + mr) * HS + g * 8];
#pragma unroll
    for (int c0 = 0; c0 < 4; c0++) {
        short8 af0 = *(const short8*)(arow + c0 * 16);
        short8 af1 = *(const short8*)(arow + 32 * HS + c0 * 16);
        acc00 = __builtin_amdgcn_mfma_f32_32x32x16_bf16(af0, bfrag[0][c0], acc00, 0, 0, 0);
        acc01 = __builtin_amdgcn_mfma_f32_32x32x16_bf16(af0, bfrag[1][c0], acc01, 0, 0, 0);
        acc10 = __builtin_amdgcn_mfma_f32_32x32x16_bf16(af1, bfrag[0][c0], acc10, 0, 0, 0);
        acc11 = __builtin_amdgcn_mfma_f32_32x32x16_bf16(af1, bfrag[1][c0], acc11, 0, 0, 0);
    }

    float bv0 = b1[mr];
    float bv1 = b1[32 + mr];
    float mx0 = -INFINITY, mx1 = -INFINITY;
#pragma unroll
    for (int mt = 0; mt < 2; mt++) {
#pragma unroll
        for (int r = 0; r < 16; r++) {
            int row = (r & 3) + 8 * (r >> 2) + 4 * g;
            int p = wave * 64 + mt * 32 + row;
            float vm = vmask[p];
            float a0 = (mt == 0) ? acc00[r] : acc10[r];
            float a1 = (mt == 0) ? acc01[r] : acc11[r];
            float v0 = (vm < 0.f) ? -INFINITY : (a0 + bv0) * vm;
            float v1 = (vm < 0.f) ? -INFINITY : (a1 + bv1) * vm;
            mx0 = fmaxf(mx0, v0);
            mx1 = fmaxf(mx1, v1);
        }
    }
    mx0 = fmaxf(mx0, __shfl_xor(mx0, 32, 64));
    mx1 = fmaxf(mx1, __shfl_xor(mx1, 32, 64));
    if (lane < 32) { red[wave][mr] = mx0; red[wave][32 + mr] = mx1; }
    __syncthreads();
    if (n < F)
        pmax[(size_t)bp * F + n] = fmaxf(red[0][n], red[1][n]);
}

// ---------------------------------------------------------------------------
// Scatter: numpy last-write-wins via atomicMax(p) + conditional write.
// ---------------------------------------------------------------------------
__global__ __launch_bounds__(256) void winner_kernel(
    const int* __restrict__ idxs, int* __restrict__ winner)
{
    int i = blockIdx.x * 256 + threadIdx.x;
    if (i >= B * P) return;
    int ix = idxs[i * 2], iy = idxs[i * 2 + 1];
    int b = i / P, p = i % P;
    atomicMax(&winner[(b * NX + ix) * NY + iy], p);
}

__global__ __launch_bounds__(64) void scatter_kernel(
    const int* __restrict__ idxs, const int* __restrict__ winner,
    const float* __restrict__ pmax, __hip_bfloat16* __restrict__ img)
{
    int bp = blockIdx.x;
    int f = threadIdx.x;
    int ix = idxs[bp * 2], iy = idxs[bp * 2 + 1];
    int b = bp / P, p = bp % P;
    int cell = (b * NX + ix) * NY + iy;
    if (winner[cell] == p)
        img[(size_t)cell * F + f] = __float2bfloat16(pmax[(size_t)bp * F + f]);
}

// ---------------------------------------------------------------------------
// Weight converts. Conv weights -> [tap][ci/16][128 co][16 ci] bf16 so a
// wave's B-fragment (32 co x 16 ci) is 1 KB contiguous.
// ---------------------------------------------------------------------------
__global__ __launch_bounds__(256) void cvt_w_kernel(
    const float* __restrict__ w, __hip_bfloat16* __restrict__ wt, int cin)
{
    int idx = blockIdx.x * 256 + threadIdx.x;
    int total = 9 * cin * 128;
    if (idx >= total) return;
    int co = idx % 128;
    int rest = idx / 128;
    int ci = rest % cin;
    int t  = rest / cin;
    int c0 = ci >> 4, c16 = ci & 15;
    wt[(((size_t)(t * (cin >> 4) + c0)) * 128 + co) * 16 + c16] = __float2bfloat16(w[idx]);
}

__global__ __launch_bounds__(256) void cvt_w1_kernel(
    const float* __restrict__ w1, __hip_bfloat16* __restrict__ w1t)
{
    int idx = blockIdx.x * 256 + threadIdx.x;
    if (idx >= F * F) return;
    int k = idx >> 6, nn = idx & 63;
    w1t[nn * F + k] = __float2bfloat16(w1[idx]);
}

// ---------------------------------------------------------------------------
// MFMA implicit-GEMM 3x3 conv, SAME, Cout=128.
// Block: 64 pixels x 128 cout, 128 threads (2 waves).
// Wave w: couts w*64..w*64+63 (2 N-tiles), all 64 px (2 M-tiles) -> 4 acc.
// Weights double-buffered in registers one tap ahead (hides L2 latency).
// ---------------------------------------------------------------------------
template<int CIN, bool FUSE, int MINW>
__global__ __launch_bounds__(128, MINW) void conv_mfma(
    const __hip_bfloat16* __restrict__ in,    // [B,240,240,CIN] bf16
    const __hip_bfloat16* __restrict__ wt,    // [9][CIN/16][128][16] bf16
    const float* __restrict__ bias,           // [128]
    const float* __restrict__ w2,             // [128] (FUSE)
    const float* __restrict__ b2,             // [1]   (FUSE)
    __hip_bfloat16* __restrict__ out_bf,
    float* __restrict__ out_f)
{
    constexpr int CPAD = CIN + 8;
    constexpr int NC16 = CIN / 16;
    __shared__ __hip_bfloat16 sP[3 * 66 * CPAD];
    __shared__ float sred[2][64];

    int tid  = threadIdx.x;
    int wave = tid >> 6;
    int lane = tid & 63;
    int mr = lane & 31;
    int g  = lane >> 5;
    int y0 = blockIdx.x * 64;
    int ix = blockIdx.y;
    int b  = blockIdx.z;
    int n0 = wave * 64;

    // ---- stage input patch [3][66][CIN] -> LDS ----
    constexpr int NC8 = CIN / 8;
    for (int t = tid; t < 3 * 66 * NC8; t += 128) {
        int c8  = t & (NC8 - 1);
        int row = t / NC8;
        int dy  = row % 66;
        int kh  = row / 66;
        int gx = ix + kh - 1, gy = y0 + dy - 1;
        float4 v = make_float4(0.f, 0.f, 0.f, 0.f);
        if (gx >= 0 && gx < NX && gy >= 0 && gy < NY)
            v = *(const float4*)&in[(((size_t)b * NX + gx) * NY + gy) * CIN + c8 * 8];
        *(float4*)&sP[row * CPAD + c8 * 8] = v;
    }

    // ---- weight prefetch: tap 0 ----
    const short* wts = (const short*)wt;
    short8 wbuf[2][NC16][2];
#pragma unroll
    for (int c0 = 0; c0 < NC16; c0++)
#pragma unroll
        for (int nt = 0; nt < 2; nt++)
            wbuf[0][c0][nt] = *(const short8*)(wts +
                ((size_t)(0 * NC16 + c0) * 128 + n0 + nt * 32 + mr) * 16 + g * 8);

    __syncthreads();

    f32x16 acc00 = {0,0,0,0,0,0,0,0,0,0,0,0,0,0,0,0};
    f32x16 acc01 = acc00, acc10 = acc00, acc11 = acc00;
    const short* sPs = (const short*)sP;

#pragma unroll
    for (int tap = 0; tap < 9; tap++) {
        int kh = tap / 3, kw = tap % 3;
        int cur = tap & 1;
        if (tap < 8) {
#pragma unroll
            for (int c0 = 0; c0 < NC16; c0++)
#pragma unroll
                for (int nt = 0; nt < 2; nt++)
                    wbuf[cur ^ 1][c0][nt] = *(const short8*)(wts +
                        ((size_t)((tap + 1) * NC16 + c0) * 128 + n0 + nt * 32 + mr) * 16 + g * 8);
        }
        int prow = (kh * 66 + kw + mr) * CPAD + g * 8;
#pragma unroll
        for (int c0 = 0; c0 < NC16; c0++) {
            short8 a0 = *(const short8*)(sPs + prow + c0 * 16);
            short8 a1 = *(const short8*)(sPs + prow + 32 * CPAD + c0 * 16);
            acc00 = __builtin_amdgcn_mfma_f32_32x32x16_bf16(a0, wbuf[cur][c0][0], acc00, 0, 0, 0);
            acc01 = __builtin_amdgcn_mfma_f32_32x32x16_bf16(a0, wbuf[cur][c0][1], acc01, 0, 0, 0);
            acc10 = __builtin_amdgcn_mfma_f32_32x32x16_bf16(a1, wbuf[cur][c0][0], acc10, 0, 0, 0);
            acc11 = __builtin_amdgcn_mfma_f32_32x32x16_bf16(a1, wbuf[cur][c0][1], acc11, 0, 0, 0);
        }
    }

    // ---- epilogue ----
    float bv0 = bias[n0 + mr];
    float bv1 = bias[n0 + 32 + mr];
    if (!FUSE) {
        size_t base = (((size_t)b * NX + ix) * NY);
#pragma unroll
        for (int mt = 0; mt < 2; mt++) {
#pragma unroll
            for (int r = 0; r < 16; r++) {
                float a0 = (mt == 0) ? acc00[r] : acc10[r];
                float a1 = (mt == 0) ? acc01[r] : acc11[r];
                int row = (r & 3) + 8 * (r >> 2) + 4 * g;
                int y = y0 + mt * 32 + row;
                if (y < NY) {
                    out_bf[(base + y) * C1 + n0 + mr]      = __float2bfloat16(tanh_fast(a0 + bv0));
                    out_bf[(base + y) * C1 + n0 + 32 + mr] = __float2bfloat16(tanh_fast(a1 + bv1));
                }
            }
        }
    } else {
        float w20 = w2[n0 + mr];
        float w21 = w2[n0 + 32 + mr];
#pragma unroll
        for (int mt = 0; mt < 2; mt++) {
#pragma unroll
            for (int r = 0; r < 16; r++) {
                float a0 = (mt == 0) ? acc00[r] : acc10[r];
                float a1 = (mt == 0) ? acc01[r] : acc11[r];
                float v = tanh_fast(a0 + bv0) * w20 + tanh_fast(a1 + bv1) * w21;
                v += __shfl_xor(v, 1, 64);
                v += __shfl_xor(v, 2, 64);
                v += __shfl_xor(v, 4, 64);
                v += __shfl_xor(v, 8, 64);
                v += __shfl_xor(v, 16, 64);
                if (mr == 0) {
                    int row = (r & 3) + 8 * (r >> 2) + 4 * g;
                    sred[wave][mt * 32 + row] = v;
                }
            }
        }
        __syncthreads();
        if (tid < 64) {
            int y = y0 + tid;
            if (y < NY) {
                float r = sred[0][tid] + sred[1][tid] + b2[0];
                out_f[((size_t)b * NX + ix) * NY + y] = fmaxf(r, 0.f);
            }
        }
    }
}

// ---------------------------------------------------------------------------
extern "C" void kernel_launch(void* const* d_in, const int* in_sizes, int n_in,
                              void* d_out, int out_size, void* d_ws, size_t ws_size,
                              hipStream_t stream) {
    const float* pillars = (const float*)d_in[0];
    const int*   idxs    = (const int*)d_in[1];
    const float* pn_w0   = (const float*)d_in[4];
    const float* pn_b0   = (const float*)d_in[5];
    const float* pn_w1   = (const float*)d_in[6];
    const float* pn_b1   = (const float*)d_in[7];
    const float* cw0     = (const float*)d_in[8];
    const float* cb0     = (const float*)d_in[9];
    const float* cw1     = (const float*)d_in[10];
    const float* cb1     = (const float*)d_in[11];
    const float* cw2     = (const float*)d_in[12];
    const float* cb2     = (const float*)d_in[13];
    float* out = (float*)d_out;

    // workspace layout
    char* ws = (char*)d_ws;
    const size_t IMG_BYTES  = (size_t)B * NX * NY * F * 2;
    const size_t OUT1_BYTES = (size_t)B * NX * NY * C1 * 2;
    const size_t WIN_BYTES  = (size_t)B * NX * NY * 4;
    const size_t PMAX_BYTES = (size_t)B * P * F * 4;
    const size_t WT1_BYTES  = (size_t)9 * C1 * F * 2;
    const size_t WT2_BYTES  = (size_t)9 * C1 * C1 * 2;
    __hip_bfloat16* img  = (__hip_bfloat16*)ws;
    __hip_bfloat16* out1 = (__hip_bfloat16*)(ws + IMG_BYTES);
    int*   winner = (int*)(ws + IMG_BYTES + OUT1_BYTES);
    float* pmax   = (float*)(ws + IMG_BYTES + OUT1_BYTES + WIN_BYTES);
    __hip_bfloat16* wt1 = (__hip_bfloat16*)(ws + IMG_BYTES + OUT1_BYTES + WIN_BYTES + PMAX_BYTES);
    __hip_bfloat16* wt2 = (__hip_bfloat16*)(ws + IMG_BYTES + OUT1_BYTES + WIN_BYTES + PMAX_BYTES + WT1_BYTES);
    __hip_bfloat16* w1t = (__hip_bfloat16*)(ws + IMG_BYTES + OUT1_BYTES + WIN_BYTES + PMAX_BYTES + WT1_BYTES + WT2_BYTES);

    hipMemsetAsync(img, 0, IMG_BYTES, stream);
    hipMemsetAsync(winner, 0xFF, WIN_BYTES, stream);   // -1

    cvt_w_kernel<<<(9 * F * C1 + 255) / 256, 256, 0, stream>>>(cw0, wt1, F);
    cvt_w_kernel<<<(9 * C1 * C1 + 255) / 256, 256, 0, stream>>>(cw1, wt2, C1);
    cvt_w1_kernel<<<(F * F + 255) / 256, 256, 0, stream>>>(pn_w1, w1t);

    pn_mfma_kernel<<<B * P, 128, 0, stream>>>(pillars, pn_w0, pn_b0, w1t, pn_b1, pmax);
    winner_kernel<<<(B * P + 255) / 256, 256, 0, stream>>>(idxs, winner);
    scatter_kernel<<<B * P, 64, 0, stream>>>(idxs, winner, pmax, img);

    conv_mfma<F, false, 2><<<dim3(4, NX, B), 128, 0, stream>>>(
        img, wt1, cb0, nullptr, nullptr, out1, nullptr);
    conv_mfma<C1, true, 1><<<dim3(4, NX, B), 128, 0, stream>>>(
        out1, wt2, cb1, cw2, cb2, nullptr, out);
}

// Round 5
// 451.502 us; speedup vs baseline: 5.4675x; 1.2343x over previous
//
#include <hip/hip_runtime.h>
#include <hip/hip_bf16.h>
#include <math.h>

// Problem constants (fixed by setup_inputs)
#define B  4
#define P  5000
#define NPT 100
#define F  64          // pointnet feature dim
#define NX 240
#define NY 240
#define C1 128         // conv1/conv2 out channels

typedef __attribute__((ext_vector_type(8)))  short short8;   // 8 bf16
typedef __attribute__((ext_vector_type(16))) float f32x16;

__device__ __forceinline__ float tanh_fast(float x) {
    float e = __expf(2.0f * x);
    return 1.0f - 2.0f / (e + 1.0f);
}
__device__ __forceinline__ short bf16_bits(float f) {
    return (short)(__bfloat16_as_ushort(__float2bfloat16(f)));
}

// ---------------------------------------------------------------------------
// PointNet with MFMA layer 2 (unchanged from R3).
// ---------------------------------------------------------------------------
__global__ __launch_bounds__(128) void pn_mfma_kernel(
    const float* __restrict__ pillars,    // [B,P,N,8]
    const float* __restrict__ w0,         // [8,64]
    const float* __restrict__ b0,         // [64]
    const __hip_bfloat16* __restrict__ w1t, // [64n][64k] bf16
    const float* __restrict__ b1,         // [64]
    float* __restrict__ pmax)             // [B*P,64]
{
    constexpr int HS = F + 8;             // 72 shorts
    __shared__ short hA[128 * HS];
    __shared__ float vmask[128];
    __shared__ float red[2][F];

    int bp = blockIdx.x;
    int n  = threadIdx.x;
    bool live = (n < NPT);

    const float* xp = pillars + ((size_t)bp * NPT + (live ? n : 0)) * 8;
    float4 q0 = *(const float4*)xp;
    float4 q1 = *(const float4*)(xp + 4);
    float x[8] = {q0.x, q0.y, q0.z, q0.w, q1.x, q1.y, q1.z, q1.w};

    float ss = 0.f;
#pragma unroll
    for (int c = 0; c < 8; c++) ss += x[c] * x[c];
    vmask[n] = live ? ((ss < 1e12f) ? 1.0f : 0.0f) : -1.0f;

    for (int j0 = 0; j0 < F; j0 += 8) {
        short8 hv;
#pragma unroll
        for (int jj = 0; jj < 8; jj++) {
            float h = b0[j0 + jj];
#pragma unroll
            for (int c = 0; c < 8; c++) h += x[c] * w0[c * F + j0 + jj];
            hv[jj] = bf16_bits(tanh_fast(h));
        }
        *(short8*)&hA[n * HS + j0] = hv;
    }
    __syncthreads();

    int wave = n >> 6, lane = n & 63;
    int mr = lane & 31;
    int g  = lane >> 5;

    short8 bfrag[2][4];
#pragma unroll
    for (int nt = 0; nt < 2; nt++)
#pragma unroll
        for (int c0 = 0; c0 < 4; c0++)
            bfrag[nt][c0] = *(const short8*)((const short*)w1t +
                                (nt * 32 + mr) * F + c0 * 16 + g * 8);

    f32x16 acc00 = {0,0,0,0,0,0,0,0,0,0,0,0,0,0,0,0};
    f32x16 acc01 = acc00, acc10 = acc00, acc11 = acc00;

    const short* arow = &hA[(wave * 64 + mr) * HS + g * 8];
#pragma unroll
    for (int c0 = 0; c0 < 4; c0++) {
        short8 af0 = *(const short8*)(arow + c0 * 16);
        short8 af1 = *(const short8*)(arow + 32 * HS + c0 * 16);
        acc00 = __builtin_amdgcn_mfma_f32_32x32x16_bf16(af0, bfrag[0][c0], acc00, 0, 0, 0);
        acc01 = __builtin_amdgcn_mfma_f32_32x32x16_bf16(af0, bfrag[1][c0], acc01, 0, 0, 0);
        acc10 = __builtin_amdgcn_mfma_f32_32x32x16_bf16(af1, bfrag[0][c0], acc10, 0, 0, 0);
        acc11 = __builtin_amdgcn_mfma_f32_32x32x16_bf16(af1, bfrag[1][c0], acc11, 0, 0, 0);
    }

    float bv0 = b1[mr];
    float bv1 = b1[32 + mr];
    float mx0 = -INFINITY, mx1 = -INFINITY;
#pragma unroll
    for (int mt = 0; mt < 2; mt++) {
#pragma unroll
        for (int r = 0; r < 16; r++) {
            int row = (r & 3) + 8 * (r >> 2) + 4 * g;
            int p = wave * 64 + mt * 32 + row;
            float vm = vmask[p];
            float a0 = (mt == 0) ? acc00[r] : acc10[r];
            float a1 = (mt == 0) ? acc01[r] : acc11[r];
            float v0 = (vm < 0.f) ? -INFINITY : (a0 + bv0) * vm;
            float v1 = (vm < 0.f) ? -INFINITY : (a1 + bv1) * vm;
            mx0 = fmaxf(mx0, v0);
            mx1 = fmaxf(mx1, v1);
        }
    }
    mx0 = fmaxf(mx0, __shfl_xor(mx0, 32, 64));
    mx1 = fmaxf(mx1, __shfl_xor(mx1, 32, 64));
    if (lane < 32) { red[wave][mr] = mx0; red[wave][32 + mr] = mx1; }
    __syncthreads();
    if (n < F)
        pmax[(size_t)bp * F + n] = fmaxf(red[0][n], red[1][n]);
}

// ---------------------------------------------------------------------------
// Scatter: numpy last-write-wins via atomicMax(p) + conditional write.
// ---------------------------------------------------------------------------
__global__ __launch_bounds__(256) void winner_kernel(
    const int* __restrict__ idxs, int* __restrict__ winner)
{
    int i = blockIdx.x * 256 + threadIdx.x;
    if (i >= B * P) return;
    int ix = idxs[i * 2], iy = idxs[i * 2 + 1];
    int b = i / P, p = i % P;
    atomicMax(&winner[(b * NX + ix) * NY + iy], p);
}

__global__ __launch_bounds__(64) void scatter_kernel(
    const int* __restrict__ idxs, const int* __restrict__ winner,
    const float* __restrict__ pmax, __hip_bfloat16* __restrict__ img)
{
    int bp = blockIdx.x;
    int f = threadIdx.x;
    int ix = idxs[bp * 2], iy = idxs[bp * 2 + 1];
    int b = bp / P, p = bp % P;
    int cell = (b * NX + ix) * NY + iy;
    if (winner[cell] == p)
        img[(size_t)cell * F + f] = __float2bfloat16(pmax[(size_t)bp * F + f]);
}

// ---------------------------------------------------------------------------
// Weight converts. Conv weights -> [tap][ci/16][128 co][16 ci] bf16.
// ---------------------------------------------------------------------------
__global__ __launch_bounds__(256) void cvt_w_kernel(
    const float* __restrict__ w, __hip_bfloat16* __restrict__ wt, int cin)
{
    int idx = blockIdx.x * 256 + threadIdx.x;
    int total = 9 * cin * 128;
    if (idx >= total) return;
    int co = idx % 128;
    int rest = idx / 128;
    int ci = rest % cin;
    int t  = rest / cin;
    int c0 = ci >> 4, c16 = ci & 15;
    wt[(((size_t)(t * (cin >> 4) + c0)) * 128 + co) * 16 + c16] = __float2bfloat16(w[idx]);
}

__global__ __launch_bounds__(256) void cvt_w1_kernel(
    const float* __restrict__ w1, __hip_bfloat16* __restrict__ w1t)
{
    int idx = blockIdx.x * 256 + threadIdx.x;
    if (idx >= F * F) return;
    int k = idx >> 6, nn = idx & 63;
    w1t[nn * F + k] = __float2bfloat16(w1[idx]);
}

// ---------------------------------------------------------------------------
// MFMA implicit-GEMM 3x3 conv, SAME, Cout=128.
// Block: 256 threads = 4 waves = 2 x-rows x 2 co-halves; 64-px y-tile.
// LDS patch: 4 x-rows x 66 y x CIN (shared by both output x-rows).
// Wave: 64 px (2 M-tiles) x 64 co (2 N-tiles) -> 4 f32x16 acc.
// Occupancy: CIN=128 -> 72KB LDS, 2 blk/CU (8 waves); CIN=64 -> 38KB, 4 blk.
// ---------------------------------------------------------------------------
template<int CIN, bool FUSE>
__global__ __launch_bounds__(256) void conv_mfma(
    const __hip_bfloat16* __restrict__ in,    // [B,240,240,CIN] bf16
    const __hip_bfloat16* __restrict__ wt,    // [9][CIN/16][128][16] bf16
    const float* __restrict__ bias,           // [128]
    const float* __restrict__ w2,             // [128] (FUSE)
    const float* __restrict__ b2,             // [1]   (FUSE)
    __hip_bfloat16* __restrict__ out_bf,
    float* __restrict__ out_f)
{
    constexpr int CPAD = CIN + 8;
    constexpr int NC16 = CIN / 16;
    constexpr int NC8  = CIN / 8;
    __shared__ __hip_bfloat16 sP[4 * 66 * CPAD];
    __shared__ float sred[4][64];

    int tid  = threadIdx.x;
    int wave = tid >> 6;
    int lane = tid & 63;
    int mr = lane & 31;
    int g  = lane >> 5;
    int xr  = wave & 1;       // output x-row within pair
    int coh = wave >> 1;      // cout half
    int y0 = blockIdx.x * 64;
    int x0 = blockIdx.y * 2;
    int b  = blockIdx.z;
    int n0 = coh * 64;

    // ---- stage input patch [4 x-rows][66 y][CIN] -> LDS ----
    for (int t = tid; t < 4 * 66 * NC8; t += 256) {
        int c8  = t & (NC8 - 1);
        int row = t / NC8;
        int dy  = row % 66;
        int dx  = row / 66;
        int gx = x0 + dx - 1, gy = y0 + dy - 1;
        float4 v = make_float4(0.f, 0.f, 0.f, 0.f);
        if (gx >= 0 && gx < NX && gy >= 0 && gy < NY)
            v = *(const float4*)&in[(((size_t)b * NX + gx) * NY + gy) * CIN + c8 * 8];
        *(float4*)&sP[row * CPAD + c8 * 8] = v;
    }

    // ---- weight prefetch: tap 0 ----
    const short* wts = (const short*)wt;
    short8 wbuf[2][NC16][2];
#pragma unroll
    for (int c0 = 0; c0 < NC16; c0++)
#pragma unroll
        for (int nt = 0; nt < 2; nt++)
            wbuf[0][c0][nt] = *(const short8*)(wts +
                ((size_t)c0 * 128 + n0 + nt * 32 + mr) * 16 + g * 8);

    __syncthreads();

    f32x16 acc00 = {0,0,0,0,0,0,0,0,0,0,0,0,0,0,0,0};
    f32x16 acc01 = acc00, acc10 = acc00, acc11 = acc00;
    const short* sPs = (const short*)sP;

#pragma unroll
    for (int tap = 0; tap < 9; tap++) {
        int kh = tap / 3, kw = tap % 3;
        int cur = tap & 1;
        if (tap < 8) {
#pragma unroll
            for (int c0 = 0; c0 < NC16; c0++)
#pragma unroll
                for (int nt = 0; nt < 2; nt++)
                    wbuf[cur ^ 1][c0][nt] = *(const short8*)(wts +
                        ((size_t)((tap + 1) * NC16 + c0) * 128 + n0 + nt * 32 + mr) * 16 + g * 8);
        }
        int prow = ((xr + kh) * 66 + kw + mr) * CPAD + g * 8;
#pragma unroll
        for (int c0 = 0; c0 < NC16; c0++) {
            short8 a0 = *(const short8*)(sPs + prow + c0 * 16);
            short8 a1 = *(const short8*)(sPs + prow + 32 * CPAD + c0 * 16);
            acc00 = __builtin_amdgcn_mfma_f32_32x32x16_bf16(a0, wbuf[cur][c0][0], acc00, 0, 0, 0);
            acc01 = __builtin_amdgcn_mfma_f32_32x32x16_bf16(a0, wbuf[cur][c0][1], acc01, 0, 0, 0);
            acc10 = __builtin_amdgcn_mfma_f32_32x32x16_bf16(a1, wbuf[cur][c0][0], acc10, 0, 0, 0);
            acc11 = __builtin_amdgcn_mfma_f32_32x32x16_bf16(a1, wbuf[cur][c0][1], acc11, 0, 0, 0);
        }
    }

    // ---- epilogue ----
    float bv0 = bias[n0 + mr];
    float bv1 = bias[n0 + 32 + mr];
    int gx = x0 + xr;
    if (!FUSE) {
        size_t base = (((size_t)b * NX + gx) * NY);
#pragma unroll
        for (int mt = 0; mt < 2; mt++) {
#pragma unroll
            for (int r = 0; r < 16; r++) {
                float a0 = (mt == 0) ? acc00[r] : acc10[r];
                float a1 = (mt == 0) ? acc01[r] : acc11[r];
                int row = (r & 3) + 8 * (r >> 2) + 4 * g;
                int y = y0 + mt * 32 + row;
                if (y < NY) {
                    out_bf[(base + y) * C1 + n0 + mr]      = __float2bfloat16(tanh_fast(a0 + bv0));
                    out_bf[(base + y) * C1 + n0 + 32 + mr] = __float2bfloat16(tanh_fast(a1 + bv1));
                }
            }
        }
    } else {
        float w20 = w2[n0 + mr];
        float w21 = w2[n0 + 32 + mr];
#pragma unroll
        for (int mt = 0; mt < 2; mt++) {
#pragma unroll
            for (int r = 0; r < 16; r++) {
                float a0 = (mt == 0) ? acc00[r] : acc10[r];
                float a1 = (mt == 0) ? acc01[r] : acc11[r];
                float v = tanh_fast(a0 + bv0) * w20 + tanh_fast(a1 + bv1) * w21;
                v += __shfl_xor(v, 1, 64);
                v += __shfl_xor(v, 2, 64);
                v += __shfl_xor(v, 4, 64);
                v += __shfl_xor(v, 8, 64);
                v += __shfl_xor(v, 16, 64);
                if (mr == 0) {
                    int row = (r & 3) + 8 * (r >> 2) + 4 * g;
                    sred[wave][mt * 32 + row] = v;
                }
            }
        }
        __syncthreads();
        if (tid < 128) {
            int xr2 = tid >> 6;
            int yy  = tid & 63;
            int y = y0 + yy;
            if (y < NY) {
                float r = sred[xr2][yy] + sred[2 + xr2][yy] + b2[0];
                out_f[((size_t)b * NX + x0 + xr2) * NY + y] = fmaxf(r, 0.f);
            }
        }
    }
}

// ---------------------------------------------------------------------------
extern "C" void kernel_launch(void* const* d_in, const int* in_sizes, int n_in,
                              void* d_out, int out_size, void* d_ws, size_t ws_size,
                              hipStream_t stream) {
    const float* pillars = (const float*)d_in[0];
    const int*   idxs    = (const int*)d_in[1];
    const float* pn_w0   = (const float*)d_in[4];
    const float* pn_b0   = (const float*)d_in[5];
    const float* pn_w1   = (const float*)d_in[6];
    const float* pn_b1   = (const float*)d_in[7];
    const float* cw0     = (const float*)d_in[8];
    const float* cb0     = (const float*)d_in[9];
    const float* cw1     = (const float*)d_in[10];
    const float* cb1     = (const float*)d_in[11];
    const float* cw2     = (const float*)d_in[12];
    const float* cb2     = (const float*)d_in[13];
    float* out = (float*)d_out;

    // workspace layout
    char* ws = (char*)d_ws;
    const size_t IMG_BYTES  = (size_t)B * NX * NY * F * 2;
    const size_t OUT1_BYTES = (size_t)B * NX * NY * C1 * 2;
    const size_t WIN_BYTES  = (size_t)B * NX * NY * 4;
    const size_t PMAX_BYTES = (size_t)B * P * F * 4;
    const size_t WT1_BYTES  = (size_t)9 * C1 * F * 2;
    const size_t WT2_BYTES  = (size_t)9 * C1 * C1 * 2;
    __hip_bfloat16* img  = (__hip_bfloat16*)ws;
    __hip_bfloat16* out1 = (__hip_bfloat16*)(ws + IMG_BYTES);
    int*   winner = (int*)(ws + IMG_BYTES + OUT1_BYTES);
    float* pmax   = (float*)(ws + IMG_BYTES + OUT1_BYTES + WIN_BYTES);
    __hip_bfloat16* wt1 = (__hip_bfloat16*)(ws + IMG_BYTES + OUT1_BYTES + WIN_BYTES + PMAX_BYTES);
    __hip_bfloat16* wt2 = (__hip_bfloat16*)(ws + IMG_BYTES + OUT1_BYTES + WIN_BYTES + PMAX_BYTES + WT1_BYTES);
    __hip_bfloat16* w1t = (__hip_bfloat16*)(ws + IMG_BYTES + OUT1_BYTES + WIN_BYTES + PMAX_BYTES + WT1_BYTES + WT2_BYTES);

    hipMemsetAsync(img, 0, IMG_BYTES, stream);
    hipMemsetAsync(winner, 0xFF, WIN_BYTES, stream);   // -1

    cvt_w_kernel<<<(9 * F * C1 + 255) / 256, 256, 0, stream>>>(cw0, wt1, F);
    cvt_w_kernel<<<(9 * C1 * C1 + 255) / 256, 256, 0, stream>>>(cw1, wt2, C1);
    cvt_w1_kernel<<<(F * F + 255) / 256, 256, 0, stream>>>(pn_w1, w1t);

    pn_mfma_kernel<<<B * P, 128, 0, stream>>>(pillars, pn_w0, pn_b0, w1t, pn_b1, pmax);
    winner_kernel<<<(B * P + 255) / 256, 256, 0, stream>>>(idxs, winner);
    scatter_kernel<<<B * P, 64, 0, stream>>>(idxs, winner, pmax, img);

    conv_mfma<F, false><<<dim3(4, NX / 2, B), 256, 0, stream>>>(
        img, wt1, cb0, nullptr, nullptr, out1, nullptr);
    conv_mfma<C1, true><<<dim3(4, NX / 2, B), 256, 0, stream>>>(
        out1, wt2, cb1, cw2, cb2, nullptr, out);
}

// Round 6
// 391.678 us; speedup vs baseline: 6.3026x; 1.1527x over previous
//
#include <hip/hip_runtime.h>
#include <hip/hip_bf16.h>
#include <math.h>

// Problem constants (fixed by setup_inputs)
#define B  4
#define P  5000
#define NPT 100
#define F  64          // pointnet feature dim
#define NX 240
#define NY 240
#define C1 128         // conv1/conv2 out channels

typedef __attribute__((ext_vector_type(8)))  short short8;   // 8 bf16
typedef __attribute__((ext_vector_type(16))) float f32x16;

// tanh via v_exp + v_rcp (rel err ~1e-6; saturates correctly at +-1)
__device__ __forceinline__ float tanh_fast(float x) {
    float e = __expf(2.0f * x);
    float r = __builtin_amdgcn_rcpf(e + 1.0f);
    return __builtin_fmaf(-2.0f, r, 1.0f);
}
__device__ __forceinline__ short bf16_bits(float f) {
    return (short)(__bfloat16_as_ushort(__float2bfloat16(f)));
}

// ---------------------------------------------------------------------------
// PointNet, both layers on MFMA.
// Block = 1 pillar, 128 threads (2 waves); points 100..127 phantoms.
// Layer 1: x (hi/lo bf16 split, fp32-accurate) @ w0 via 2 MFMA/tile, K=32:
//   A slots [x_hi(8)|x_lo(8)|x_hi(8)|0], B slots [w_hi|w_hi|w_lo|0].
// tanh in C-layout -> hA[point][feat] bf16 -> layer 2 MFMA (as R3-R5).
// ---------------------------------------------------------------------------
__global__ __launch_bounds__(128) void pn_mfma_kernel(
    const float* __restrict__ pillars,    // [B,P,N,8]
    const float* __restrict__ w0,         // [8,64]
    const float* __restrict__ b0,         // [64]
    const __hip_bfloat16* __restrict__ w1t, // [64n][64k] bf16
    const float* __restrict__ b1,         // [64]
    float* __restrict__ pmax)             // [B*P,64]
{
    constexpr int HS = F + 8;             // 72 shorts
    constexpr int XS = 32;                // K=32 slots/point
    __shared__ short xA[128 * XS];        // 8 KB
    __shared__ short hA[128 * HS];        // 18 KB
    __shared__ float vmask[128];
    __shared__ float red[2][F];

    int bp = blockIdx.x;
    int n  = threadIdx.x;
    bool live = (n < NPT);

    const float* xp = pillars + ((size_t)bp * NPT + (live ? n : 0)) * 8;
    float4 q0 = *(const float4*)xp;
    float4 q1 = *(const float4*)(xp + 4);
    float x[8] = {q0.x, q0.y, q0.z, q0.w, q1.x, q1.y, q1.z, q1.w};

    float ss = 0.f;
#pragma unroll
    for (int c = 0; c < 8; c++) ss += x[c] * x[c];
    vmask[n] = live ? ((ss < 1e12f) ? 1.0f : 0.0f) : -1.0f;

    // hi/lo split of x -> xA row [hi|lo|hi|0]
    short8 xhi, xlo, xz;
#pragma unroll
    for (int c = 0; c < 8; c++) {
        __hip_bfloat16 hb = __float2bfloat16(x[c]);
        float hv = __bfloat162float(hb);
        xhi[c] = (short)__bfloat16_as_ushort(hb);
        xlo[c] = bf16_bits(x[c] - hv);
        xz[c] = 0;
    }
    *(short8*)&xA[n * XS + 0]  = xhi;
    *(short8*)&xA[n * XS + 8]  = xlo;
    *(short8*)&xA[n * XS + 16] = xhi;
    *(short8*)&xA[n * XS + 24] = xz;
    __syncthreads();

    int wave = n >> 6, lane = n & 63;
    int mr = lane & 31;
    int g  = lane >> 5;

    // ---- layer-1 B fragments from global w0 (fp32) ----
    short8 wb[2][2];   // [kk][nt]
#pragma unroll
    for (int nt = 0; nt < 2; nt++) {
        int nn = nt * 32 + mr;
#pragma unroll
        for (int j = 0; j < 8; j++) {
            float wv = w0[j * F + nn];
            __hip_bfloat16 hb = __float2bfloat16(wv);
            wb[0][nt][j] = (short)__bfloat16_as_ushort(hb);               // w_hi (both g)
            wb[1][nt][j] = (g == 0) ? bf16_bits(wv - __bfloat162float(hb)) : (short)0; // w_lo / 0
        }
    }

    // ---- layer-1 MFMA: 2 M-tiles x 2 N-tiles x 2 kk ----
    f32x16 hc00 = {0,0,0,0,0,0,0,0,0,0,0,0,0,0,0,0};
    f32x16 hc01 = hc00, hc10 = hc00, hc11 = hc00;
#pragma unroll
    for (int kk = 0; kk < 2; kk++) {
        short8 a0 = *(const short8*)&xA[(wave * 64 + mr) * XS + kk * 16 + g * 8];
        short8 a1 = *(const short8*)&xA[(wave * 64 + 32 + mr) * XS + kk * 16 + g * 8];
        hc00 = __builtin_amdgcn_mfma_f32_32x32x16_bf16(a0, wb[kk][0], hc00, 0, 0, 0);
        hc01 = __builtin_amdgcn_mfma_f32_32x32x16_bf16(a0, wb[kk][1], hc01, 0, 0, 0);
        hc10 = __builtin_amdgcn_mfma_f32_32x32x16_bf16(a1, wb[kk][0], hc10, 0, 0, 0);
        hc11 = __builtin_amdgcn_mfma_f32_32x32x16_bf16(a1, wb[kk][1], hc11, 0, 0, 0);
    }

    // ---- tanh(+b0) and scatter to hA[point][feat] ----
    float b00 = b0[mr];
    float b01 = b0[32 + mr];
#pragma unroll
    for (int mt = 0; mt < 2; mt++) {
#pragma unroll
        for (int r = 0; r < 16; r++) {
            int prow = wave * 64 + mt * 32 + (r & 3) + 8 * (r >> 2) + 4 * g;
            float h0 = (mt == 0) ? hc00[r] : hc10[r];
            float h1 = (mt == 0) ? hc01[r] : hc11[r];
            hA[prow * HS + mr]      = bf16_bits(tanh_fast(h0 + b00));
            hA[prow * HS + 32 + mr] = bf16_bits(tanh_fast(h1 + b01));
        }
    }
    __syncthreads();

    // ---- layer 2 MFMA (unchanged) ----
    short8 bfrag[2][4];
#pragma unroll
    for (int nt = 0; nt < 2; nt++)
#pragma unroll
        for (int c0 = 0; c0 < 4; c0++)
            bfrag[nt][c0] = *(const short8*)((const short*)w1t +
                                (nt * 32 + mr) * F + c0 * 16 + g * 8);

    f32x16 acc00 = {0,0,0,0,0,0,0,0,0,0,0,0,0,0,0,0};
    f32x16 acc01 = acc00, acc10 = acc00, acc11 = acc00;

    const short* arow = &hA[(wave * 64 + mr) * HS + g * 8];
#pragma unroll
    for (int c0 = 0; c0 < 4; c0++) {
        short8 af0 = *(const short8*)(arow + c0 * 16);
        short8 af1 = *(const short8*)(arow + 32 * HS + c0 * 16);
        acc00 = __builtin_amdgcn_mfma_f32_32x32x16_bf16(af0, bfrag[0][c0], acc00, 0, 0, 0);
        acc01 = __builtin_amdgcn_mfma_f32_32x32x16_bf16(af0, bfrag[1][c0], acc01, 0, 0, 0);
        acc10 = __builtin_amdgcn_mfma_f32_32x32x16_bf16(af1, bfrag[0][c0], acc10, 0, 0, 0);
        acc11 = __builtin_amdgcn_mfma_f32_32x32x16_bf16(af1, bfrag[1][c0], acc11, 0, 0, 0);
    }

    float bv0 = b1[mr];
    float bv1 = b1[32 + mr];
    float mx0 = -INFINITY, mx1 = -INFINITY;
#pragma unroll
    for (int mt = 0; mt < 2; mt++) {
#pragma unroll
        for (int r = 0; r < 16; r++) {
            int row = (r & 3) + 8 * (r >> 2) + 4 * g;
            int p = wave * 64 + mt * 32 + row;
            float vm = vmask[p];
            float a0 = (mt == 0) ? acc00[r] : acc10[r];
            float a1 = (mt == 0) ? acc01[r] : acc11[r];
            float v0 = (vm < 0.f) ? -INFINITY : (a0 + bv0) * vm;
            float v1 = (vm < 0.f) ? -INFINITY : (a1 + bv1) * vm;
            mx0 = fmaxf(mx0, v0);
            mx1 = fmaxf(mx1, v1);
        }
    }
    mx0 = fmaxf(mx0, __shfl_xor(mx0, 32, 64));
    mx1 = fmaxf(mx1, __shfl_xor(mx1, 32, 64));
    if (lane < 32) { red[wave][mr] = mx0; red[wave][32 + mr] = mx1; }
    __syncthreads();
    if (n < F)
        pmax[(size_t)bp * F + n] = fmaxf(red[0][n], red[1][n]);
}

// ---------------------------------------------------------------------------
// Scatter: numpy last-write-wins via atomicMax(p) + conditional write.
// ---------------------------------------------------------------------------
__global__ __launch_bounds__(256) void winner_kernel(
    const int* __restrict__ idxs, int* __restrict__ winner)
{
    int i = blockIdx.x * 256 + threadIdx.x;
    if (i >= B * P) return;
    int ix = idxs[i * 2], iy = idxs[i * 2 + 1];
    int b = i / P, p = i % P;
    atomicMax(&winner[(b * NX + ix) * NY + iy], p);
}

__global__ __launch_bounds__(64) void scatter_kernel(
    const int* __restrict__ idxs, const int* __restrict__ winner,
    const float* __restrict__ pmax, __hip_bfloat16* __restrict__ img)
{
    int bp = blockIdx.x;
    int f = threadIdx.x;
    int ix = idxs[bp * 2], iy = idxs[bp * 2 + 1];
    int b = bp / P, p = bp % P;
    int cell = (b * NX + ix) * NY + iy;
    if (winner[cell] == p)
        img[(size_t)cell * F + f] = __float2bfloat16(pmax[(size_t)bp * F + f]);
}

// ---------------------------------------------------------------------------
// Weight converts. Conv weights -> [tap][ci/16][128 co][16 ci] bf16.
// ---------------------------------------------------------------------------
__global__ __launch_bounds__(256) void cvt_w_kernel(
    const float* __restrict__ w, __hip_bfloat16* __restrict__ wt, int cin)
{
    int idx = blockIdx.x * 256 + threadIdx.x;
    int total = 9 * cin * 128;
    if (idx >= total) return;
    int co = idx % 128;
    int rest = idx / 128;
    int ci = rest % cin;
    int t  = rest / cin;
    int c0 = ci >> 4, c16 = ci & 15;
    wt[(((size_t)(t * (cin >> 4) + c0)) * 128 + co) * 16 + c16] = __float2bfloat16(w[idx]);
}

__global__ __launch_bounds__(256) void cvt_w1_kernel(
    const float* __restrict__ w1, __hip_bfloat16* __restrict__ w1t)
{
    int idx = blockIdx.x * 256 + threadIdx.x;
    if (idx >= F * F) return;
    int k = idx >> 6, nn = idx & 63;
    w1t[nn * F + k] = __float2bfloat16(w1[idx]);
}

// ---------------------------------------------------------------------------
// MFMA implicit-GEMM 3x3 conv, SAME, Cout=128 (structure from R5).
// Block: 256 threads = 4 waves = 2 x-rows x 2 co-halves; 64-px y-tile.
// ---------------------------------------------------------------------------
template<int CIN, bool FUSE>
__global__ __launch_bounds__(256) void conv_mfma(
    const __hip_bfloat16* __restrict__ in,    // [B,240,240,CIN] bf16
    const __hip_bfloat16* __restrict__ wt,    // [9][CIN/16][128][16] bf16
    const float* __restrict__ bias,           // [128]
    const float* __restrict__ w2,             // [128] (FUSE)
    const float* __restrict__ b2,             // [1]   (FUSE)
    __hip_bfloat16* __restrict__ out_bf,
    float* __restrict__ out_f)
{
    constexpr int CPAD = CIN + 8;
    constexpr int NC16 = CIN / 16;
    constexpr int NC8  = CIN / 8;
    __shared__ __hip_bfloat16 sP[4 * 66 * CPAD];
    __shared__ float sred[4][64];

    int tid  = threadIdx.x;
    int wave = tid >> 6;
    int lane = tid & 63;
    int mr = lane & 31;
    int g  = lane >> 5;
    int xr  = wave & 1;       // output x-row within pair
    int coh = wave >> 1;      // cout half
    int y0 = blockIdx.x * 64;
    int x0 = blockIdx.y * 2;
    int b  = blockIdx.z;
    int n0 = coh * 64;

    for (int t = tid; t < 4 * 66 * NC8; t += 256) {
        int c8  = t & (NC8 - 1);
        int row = t / NC8;
        int dy  = row % 66;
        int dx  = row / 66;
        int gx = x0 + dx - 1, gy = y0 + dy - 1;
        float4 v = make_float4(0.f, 0.f, 0.f, 0.f);
        if (gx >= 0 && gx < NX && gy >= 0 && gy < NY)
            v = *(const float4*)&in[(((size_t)b * NX + gx) * NY + gy) * CIN + c8 * 8];
        *(float4*)&sP[row * CPAD + c8 * 8] = v;
    }

    const short* wts = (const short*)wt;
    short8 wbuf[2][NC16][2];
#pragma unroll
    for (int c0 = 0; c0 < NC16; c0++)
#pragma unroll
        for (int nt = 0; nt < 2; nt++)
            wbuf[0][c0][nt] = *(const short8*)(wts +
                ((size_t)c0 * 128 + n0 + nt * 32 + mr) * 16 + g * 8);

    __syncthreads();

    f32x16 acc00 = {0,0,0,0,0,0,0,0,0,0,0,0,0,0,0,0};
    f32x16 acc01 = acc00, acc10 = acc00, acc11 = acc00;
    const short* sPs = (const short*)sP;

#pragma unroll
    for (int tap = 0; tap < 9; tap++) {
        int kh = tap / 3, kw = tap % 3;
        int cur = tap & 1;
        if (tap < 8) {
#pragma unroll
            for (int c0 = 0; c0 < NC16; c0++)
#pragma unroll
                for (int nt = 0; nt < 2; nt++)
                    wbuf[cur ^ 1][c0][nt] = *(const short8*)(wts +
                        ((size_t)((tap + 1) * NC16 + c0) * 128 + n0 + nt * 32 + mr) * 16 + g * 8);
        }
        int prow = ((xr + kh) * 66 + kw + mr) * CPAD + g * 8;
#pragma unroll
        for (int c0 = 0; c0 < NC16; c0++) {
            short8 a0 = *(const short8*)(sPs + prow + c0 * 16);
            short8 a1 = *(const short8*)(sPs + prow + 32 * CPAD + c0 * 16);
            acc00 = __builtin_amdgcn_mfma_f32_32x32x16_bf16(a0, wbuf[cur][c0][0], acc00, 0, 0, 0);
            acc01 = __builtin_amdgcn_mfma_f32_32x32x16_bf16(a0, wbuf[cur][c0][1], acc01, 0, 0, 0);
            acc10 = __builtin_amdgcn_mfma_f32_32x32x16_bf16(a1, wbuf[cur][c0][0], acc10, 0, 0, 0);
            acc11 = __builtin_amdgcn_mfma_f32_32x32x16_bf16(a1, wbuf[cur][c0][1], acc11, 0, 0, 0);
        }
    }

    float bv0 = bias[n0 + mr];
    float bv1 = bias[n0 + 32 + mr];
    int gx = x0 + xr;
    if (!FUSE) {
        size_t base = (((size_t)b * NX + gx) * NY);
#pragma unroll
        for (int mt = 0; mt < 2; mt++) {
#pragma unroll
            for (int r = 0; r < 16; r++) {
                float a0 = (mt == 0) ? acc00[r] : acc10[r];
                float a1 = (mt == 0) ? acc01[r] : acc11[r];
                int row = (r & 3) + 8 * (r >> 2) + 4 * g;
                int y = y0 + mt * 32 + row;
                if (y < NY) {
                    out_bf[(base + y) * C1 + n0 + mr]      = __float2bfloat16(tanh_fast(a0 + bv0));
                    out_bf[(base + y) * C1 + n0 + 32 + mr] = __float2bfloat16(tanh_fast(a1 + bv1));
                }
            }
        }
    } else {
        float w20 = w2[n0 + mr];
        float w21 = w2[n0 + 32 + mr];
#pragma unroll
        for (int mt = 0; mt < 2; mt++) {
#pragma unroll
            for (int r = 0; r < 16; r++) {
                float a0 = (mt == 0) ? acc00[r] : acc10[r];
                float a1 = (mt == 0) ? acc01[r] : acc11[r];
                float v = tanh_fast(a0 + bv0) * w20 + tanh_fast(a1 + bv1) * w21;
                v += __shfl_xor(v, 1, 64);
                v += __shfl_xor(v, 2, 64);
                v += __shfl_xor(v, 4, 64);
                v += __shfl_xor(v, 8, 64);
                v += __shfl_xor(v, 16, 64);
                if (mr == 0) {
                    int row = (r & 3) + 8 * (r >> 2) + 4 * g;
                    sred[wave][mt * 32 + row] = v;
                }
            }
        }
        __syncthreads();
        if (tid < 128) {
            int xr2 = tid >> 6;
            int yy  = tid & 63;
            int y = y0 + yy;
            if (y < NY) {
                float r = sred[xr2][yy] + sred[2 + xr2][yy] + b2[0];
                out_f[((size_t)b * NX + x0 + xr2) * NY + y] = fmaxf(r, 0.f);
            }
        }
    }
}

// ---------------------------------------------------------------------------
extern "C" void kernel_launch(void* const* d_in, const int* in_sizes, int n_in,
                              void* d_out, int out_size, void* d_ws, size_t ws_size,
                              hipStream_t stream) {
    const float* pillars = (const float*)d_in[0];
    const int*   idxs    = (const int*)d_in[1];
    const float* pn_w0   = (const float*)d_in[4];
    const float* pn_b0   = (const float*)d_in[5];
    const float* pn_w1   = (const float*)d_in[6];
    const float* pn_b1   = (const float*)d_in[7];
    const float* cw0     = (const float*)d_in[8];
    const float* cb0     = (const float*)d_in[9];
    const float* cw1     = (const float*)d_in[10];
    const float* cb1     = (const float*)d_in[11];
    const float* cw2     = (const float*)d_in[12];
    const float* cb2     = (const float*)d_in[13];
    float* out = (float*)d_out;

    // workspace layout
    char* ws = (char*)d_ws;
    const size_t IMG_BYTES  = (size_t)B * NX * NY * F * 2;
    const size_t OUT1_BYTES = (size_t)B * NX * NY * C1 * 2;
    const size_t WIN_BYTES  = (size_t)B * NX * NY * 4;
    const size_t PMAX_BYTES = (size_t)B * P * F * 4;
    const size_t WT1_BYTES  = (size_t)9 * C1 * F * 2;
    const size_t WT2_BYTES  = (size_t)9 * C1 * C1 * 2;
    __hip_bfloat16* img  = (__hip_bfloat16*)ws;
    __hip_bfloat16* out1 = (__hip_bfloat16*)(ws + IMG_BYTES);
    int*   winner = (int*)(ws + IMG_BYTES + OUT1_BYTES);
    float* pmax   = (float*)(ws + IMG_BYTES + OUT1_BYTES + WIN_BYTES);
    __hip_bfloat16* wt1 = (__hip_bfloat16*)(ws + IMG_BYTES + OUT1_BYTES + WIN_BYTES + PMAX_BYTES);
    __hip_bfloat16* wt2 = (__hip_bfloat16*)(ws + IMG_BYTES + OUT1_BYTES + WIN_BYTES + PMAX_BYTES + WT1_BYTES);
    __hip_bfloat16* w1t = (__hip_bfloat16*)(ws + IMG_BYTES + OUT1_BYTES + WIN_BYTES + PMAX_BYTES + WT1_BYTES + WT2_BYTES);

    hipMemsetAsync(img, 0, IMG_BYTES, stream);
    hipMemsetAsync(winner, 0xFF, WIN_BYTES, stream);   // -1

    cvt_w_kernel<<<(9 * F * C1 + 255) / 256, 256, 0, stream>>>(cw0, wt1, F);
    cvt_w_kernel<<<(9 * C1 * C1 + 255) / 256, 256, 0, stream>>>(cw1, wt2, C1);
    cvt_w1_kernel<<<(F * F + 255) / 256, 256, 0, stream>>>(pn_w1, w1t);

    pn_mfma_kernel<<<B * P, 128, 0, stream>>>(pillars, pn_w0, pn_b0, w1t, pn_b1, pmax);
    winner_kernel<<<(B * P + 255) / 256, 256, 0, stream>>>(idxs, winner);
    scatter_kernel<<<B * P, 64, 0, stream>>>(idxs, winner, pmax, img);

    conv_mfma<F, false><<<dim3(4, NX / 2, B), 256, 0, stream>>>(
        img, wt1, cb0, nullptr, nullptr, out1, nullptr);
    conv_mfma<C1, true><<<dim3(4, NX / 2, B), 256, 0, stream>>>(
        out1, wt2, cb1, cw2, cb2, nullptr, out);
}

// Round 7
// 375.551 us; speedup vs baseline: 6.5733x; 1.0429x over previous
//
#include <hip/hip_runtime.h>
#include <hip/hip_bf16.h>
#include <math.h>

// Problem constants (fixed by setup_inputs)
#define B  4
#define P  5000
#define NPT 100
#define F  64          // pointnet feature dim
#define NX 240
#define NY 240
#define C1 128         // conv1/conv2 out channels

typedef __attribute__((ext_vector_type(8)))  short short8;   // 8 bf16
typedef __attribute__((ext_vector_type(16))) float f32x16;

// tanh via v_exp + v_rcp (rel err ~1e-6; saturates correctly at +-1)
__device__ __forceinline__ float tanh_fast(float x) {
    float e = __expf(2.0f * x);
    float r = __builtin_amdgcn_rcpf(e + 1.0f);
    return __builtin_fmaf(-2.0f, r, 1.0f);
}
__device__ __forceinline__ short bf16_bits(float f) {
    return (short)(__bfloat16_as_ushort(__float2bfloat16(f)));
}

// ---------------------------------------------------------------------------
// PointNet, both layers on MFMA (unchanged from R6).
// ---------------------------------------------------------------------------
__global__ __launch_bounds__(128) void pn_mfma_kernel(
    const float* __restrict__ pillars,    // [B,P,N,8]
    const float* __restrict__ w0,         // [8,64]
    const float* __restrict__ b0,         // [64]
    const __hip_bfloat16* __restrict__ w1t, // [64n][64k] bf16
    const float* __restrict__ b1,         // [64]
    float* __restrict__ pmax)             // [B*P,64]
{
    constexpr int HS = F + 8;             // 72 shorts
    constexpr int XS = 32;                // K=32 slots/point
    __shared__ short xA[128 * XS];
    __shared__ short hA[128 * HS];
    __shared__ float vmask[128];
    __shared__ float red[2][F];

    int bp = blockIdx.x;
    int n  = threadIdx.x;
    bool live = (n < NPT);

    const float* xp = pillars + ((size_t)bp * NPT + (live ? n : 0)) * 8;
    float4 q0 = *(const float4*)xp;
    float4 q1 = *(const float4*)(xp + 4);
    float x[8] = {q0.x, q0.y, q0.z, q0.w, q1.x, q1.y, q1.z, q1.w};

    float ss = 0.f;
#pragma unroll
    for (int c = 0; c < 8; c++) ss += x[c] * x[c];
    vmask[n] = live ? ((ss < 1e12f) ? 1.0f : 0.0f) : -1.0f;

    short8 xhi, xlo, xz;
#pragma unroll
    for (int c = 0; c < 8; c++) {
        __hip_bfloat16 hb = __float2bfloat16(x[c]);
        float hv = __bfloat162float(hb);
        xhi[c] = (short)__bfloat16_as_ushort(hb);
        xlo[c] = bf16_bits(x[c] - hv);
        xz[c] = 0;
    }
    *(short8*)&xA[n * XS + 0]  = xhi;
    *(short8*)&xA[n * XS + 8]  = xlo;
    *(short8*)&xA[n * XS + 16] = xhi;
    *(short8*)&xA[n * XS + 24] = xz;
    __syncthreads();

    int wave = n >> 6, lane = n & 63;
    int mr = lane & 31;
    int g  = lane >> 5;

    short8 wb[2][2];   // [kk][nt]
#pragma unroll
    for (int nt = 0; nt < 2; nt++) {
        int nn = nt * 32 + mr;
#pragma unroll
        for (int j = 0; j < 8; j++) {
            float wv = w0[j * F + nn];
            __hip_bfloat16 hb = __float2bfloat16(wv);
            wb[0][nt][j] = (short)__bfloat16_as_ushort(hb);
            wb[1][nt][j] = (g == 0) ? bf16_bits(wv - __bfloat162float(hb)) : (short)0;
        }
    }

    f32x16 hc00 = {0,0,0,0,0,0,0,0,0,0,0,0,0,0,0,0};
    f32x16 hc01 = hc00, hc10 = hc00, hc11 = hc00;
#pragma unroll
    for (int kk = 0; kk < 2; kk++) {
        short8 a0 = *(const short8*)&xA[(wave * 64 + mr) * XS + kk * 16 + g * 8];
        short8 a1 = *(const short8*)&xA[(wave * 64 + 32 + mr) * XS + kk * 16 + g * 8];
        hc00 = __builtin_amdgcn_mfma_f32_32x32x16_bf16(a0, wb[kk][0], hc00, 0, 0, 0);
        hc01 = __builtin_amdgcn_mfma_f32_32x32x16_bf16(a0, wb[kk][1], hc01, 0, 0, 0);
        hc10 = __builtin_amdgcn_mfma_f32_32x32x16_bf16(a1, wb[kk][0], hc10, 0, 0, 0);
        hc11 = __builtin_amdgcn_mfma_f32_32x32x16_bf16(a1, wb[kk][1], hc11, 0, 0, 0);
    }

    float b00 = b0[mr];
    float b01 = b0[32 + mr];
#pragma unroll
    for (int mt = 0; mt < 2; mt++) {
#pragma unroll
        for (int r = 0; r < 16; r++) {
            int prow = wave * 64 + mt * 32 + (r & 3) + 8 * (r >> 2) + 4 * g;
            float h0 = (mt == 0) ? hc00[r] : hc10[r];
            float h1 = (mt == 0) ? hc01[r] : hc11[r];
            hA[prow * HS + mr]      = bf16_bits(tanh_fast(h0 + b00));
            hA[prow * HS + 32 + mr] = bf16_bits(tanh_fast(h1 + b01));
        }
    }
    __syncthreads();

    short8 bfrag[2][4];
#pragma unroll
    for (int nt = 0; nt < 2; nt++)
#pragma unroll
        for (int c0 = 0; c0 < 4; c0++)
            bfrag[nt][c0] = *(const short8*)((const short*)w1t +
                                (nt * 32 + mr) * F + c0 * 16 + g * 8);

    f32x16 acc00 = {0,0,0,0,0,0,0,0,0,0,0,0,0,0,0,0};
    f32x16 acc01 = acc00, acc10 = acc00, acc11 = acc00;

    const short* arow = &hA[(wave * 64 + mr) * HS + g * 8];
#pragma unroll
    for (int c0 = 0; c0 < 4; c0++) {
        short8 af0 = *(const short8*)(arow + c0 * 16);
        short8 af1 = *(const short8*)(arow + 32 * HS + c0 * 16);
        acc00 = __builtin_amdgcn_mfma_f32_32x32x16_bf16(af0, bfrag[0][c0], acc00, 0, 0, 0);
        acc01 = __builtin_amdgcn_mfma_f32_32x32x16_bf16(af0, bfrag[1][c0], acc01, 0, 0, 0);
        acc10 = __builtin_amdgcn_mfma_f32_32x32x16_bf16(af1, bfrag[0][c0], acc10, 0, 0, 0);
        acc11 = __builtin_amdgcn_mfma_f32_32x32x16_bf16(af1, bfrag[1][c0], acc11, 0, 0, 0);
    }

    float bv0 = b1[mr];
    float bv1 = b1[32 + mr];
    float mx0 = -INFINITY, mx1 = -INFINITY;
#pragma unroll
    for (int mt = 0; mt < 2; mt++) {
#pragma unroll
        for (int r = 0; r < 16; r++) {
            int row = (r & 3) + 8 * (r >> 2) + 4 * g;
            int p = wave * 64 + mt * 32 + row;
            float vm = vmask[p];
            float a0 = (mt == 0) ? acc00[r] : acc10[r];
            float a1 = (mt == 0) ? acc01[r] : acc11[r];
            float v0 = (vm < 0.f) ? -INFINITY : (a0 + bv0) * vm;
            float v1 = (vm < 0.f) ? -INFINITY : (a1 + bv1) * vm;
            mx0 = fmaxf(mx0, v0);
            mx1 = fmaxf(mx1, v1);
        }
    }
    mx0 = fmaxf(mx0, __shfl_xor(mx0, 32, 64));
    mx1 = fmaxf(mx1, __shfl_xor(mx1, 32, 64));
    if (lane < 32) { red[wave][mr] = mx0; red[wave][32 + mr] = mx1; }
    __syncthreads();
    if (n < F)
        pmax[(size_t)bp * F + n] = fmaxf(red[0][n], red[1][n]);
}

// ---------------------------------------------------------------------------
// Scatter: numpy last-write-wins via atomicMax(p) + conditional write.
// ---------------------------------------------------------------------------
__global__ __launch_bounds__(256) void winner_kernel(
    const int* __restrict__ idxs, int* __restrict__ winner)
{
    int i = blockIdx.x * 256 + threadIdx.x;
    if (i >= B * P) return;
    int ix = idxs[i * 2], iy = idxs[i * 2 + 1];
    int b = i / P, p = i % P;
    atomicMax(&winner[(b * NX + ix) * NY + iy], p);
}

__global__ __launch_bounds__(64) void scatter_kernel(
    const int* __restrict__ idxs, const int* __restrict__ winner,
    const float* __restrict__ pmax, __hip_bfloat16* __restrict__ img)
{
    int bp = blockIdx.x;
    int f = threadIdx.x;
    int ix = idxs[bp * 2], iy = idxs[bp * 2 + 1];
    int b = bp / P, p = bp % P;
    int cell = (b * NX + ix) * NY + iy;
    if (winner[cell] == p)
        img[(size_t)cell * F + f] = __float2bfloat16(pmax[(size_t)bp * F + f]);
}

// ---------------------------------------------------------------------------
// Weight converts. Conv weights -> [tap][ci/16][128 co][16 ci] bf16.
// ---------------------------------------------------------------------------
__global__ __launch_bounds__(256) void cvt_w_kernel(
    const float* __restrict__ w, __hip_bfloat16* __restrict__ wt, int cin)
{
    int idx = blockIdx.x * 256 + threadIdx.x;
    int total = 9 * cin * 128;
    if (idx >= total) return;
    int co = idx % 128;
    int rest = idx / 128;
    int ci = rest % cin;
    int t  = rest / cin;
    int c0 = ci >> 4, c16 = ci & 15;
    wt[(((size_t)(t * (cin >> 4) + c0)) * 128 + co) * 16 + c16] = __float2bfloat16(w[idx]);
}

__global__ __launch_bounds__(256) void cvt_w1_kernel(
    const float* __restrict__ w1, __hip_bfloat16* __restrict__ w1t)
{
    int idx = blockIdx.x * 256 + threadIdx.x;
    if (idx >= F * F) return;
    int k = idx >> 6, nn = idx & 63;
    w1t[nn * F + k] = __float2bfloat16(w1[idx]);
}

// ---------------------------------------------------------------------------
// MFMA implicit-GEMM 3x3 conv, SAME, Cout=128. Big-y blocks:
// Block: 256 thr = 4 waves = 2 x-rows x 2 co-halves. Tile: 2x x 128y x 128co.
// Wave: 128 y (4 M-tiles) x 64 co (2 N-tiles) -> 8 f32x16 acc (128 VGPR).
// K processed in PASSES=CIN/64 passes of 64 ci through one LDS patch
// (4 x-rows x 130 y x 72 shorts = 74.9 KB); acc persists across passes.
// Weight B-frags double-buffered one tap ahead (L2 stream ~32 B/cyc/CU).
// y-tiles at y0 = {0, 112}: 16-row overlap writes identical values (benign).
// ---------------------------------------------------------------------------
template<int CIN, bool FUSE>
__global__ __launch_bounds__(256, 2) void conv_mfma(
    const __hip_bfloat16* __restrict__ in,    // [B,240,240,CIN] bf16
    const __hip_bfloat16* __restrict__ wt,    // [9][CIN/16][128][16] bf16
    const float* __restrict__ bias,           // [128]
    const float* __restrict__ w2,             // [128] (FUSE)
    const float* __restrict__ b2,             // [1]   (FUSE)
    __hip_bfloat16* __restrict__ out_bf,
    float* __restrict__ out_f)
{
    constexpr int PASSES = CIN / 64;
    constexpr int CI   = 64;              // ci per pass
    constexpr int CPAD = CI + 8;          // 72 shorts -> conflict-free stride
    constexpr int NC16 = CI / 16;         // 4
    constexpr int NC8  = CI / 8;          // 8
    constexpr int ROWS = 4 * 130;         // 520
    __shared__ short sP[ROWS * CPAD];     // 74,880 B
    __shared__ float sred[FUSE ? 2 : 1][2][128];

    int tid  = threadIdx.x;
    int wave = tid >> 6;
    int lane = tid & 63;
    int mr = lane & 31;
    int g  = lane >> 5;
    int coh = wave & 1;        // cout half
    int xr  = wave >> 1;       // output x-row within pair
    int x0 = blockIdx.x * 2;
    int y0 = blockIdx.y * 112; // 0 or 112 (tiles overlap by 16 rows)
    int b  = blockIdx.z;
    int n0 = coh * 64;

    const short* wts = (const short*)wt;

    f32x16 acc[4][2];
#pragma unroll
    for (int mt = 0; mt < 4; mt++)
#pragma unroll
        for (int nt = 0; nt < 2; nt++)
            acc[mt][nt] = (f32x16){0,0,0,0,0,0,0,0,0,0,0,0,0,0,0,0};

    // weight double-buffer; prefetch step 0 (pass 0, tap 0)
    short8 wbuf[2][NC16][2];
#pragma unroll
    for (int c0 = 0; c0 < NC16; c0++)
#pragma unroll
        for (int nt = 0; nt < 2; nt++)
            wbuf[0][c0][nt] = *(const short8*)(wts +
                ((0 * (CIN / 16) + c0) * 128 + n0 + nt * 32 + mr) * 16 + g * 8);

#pragma unroll
    for (int p = 0; p < PASSES; p++) {
        if (p) __syncthreads();   // previous pass's reads done before overwrite

        // ---- stage pass p: [4 x-rows][130 y][64 ci] -> LDS ----
#pragma unroll 4
        for (int i = 0; i < 17; i++) {
            int t = tid + i * 256;
            if (t < ROWS * NC8) {
                int c8 = t & (NC8 - 1);
                int r  = t >> 3;
                int dx = r / 130, dy = r - dx * 130;
                int gx = x0 - 1 + dx, gy = y0 - 1 + dy;
                float4 v = make_float4(0.f, 0.f, 0.f, 0.f);
                if (gx >= 0 && gx < NX && gy >= 0 && gy < NY)
                    v = *(const float4*)&in[(((size_t)b * NX + gx) * NY + gy) * CIN + p * CI + c8 * 8];
                *(float4*)&sP[r * CPAD + c8 * 8] = v;
            }
        }
        __syncthreads();

        // ---- K-loop: 9 taps of this pass ----
#pragma unroll
        for (int tap = 0; tap < 9; tap++) {
            int s = p * 9 + tap;
            int cur = s & 1;
            if (s + 1 < 9 * PASSES) {
                int sn = s + 1, pn_ = sn / 9, tn = sn % 9;
#pragma unroll
                for (int c0 = 0; c0 < NC16; c0++)
#pragma unroll
                    for (int nt = 0; nt < 2; nt++)
                        wbuf[cur ^ 1][c0][nt] = *(const short8*)(wts +
                            ((tn * (CIN / 16) + pn_ * NC16 + c0) * 128 + n0 + nt * 32 + mr) * 16 + g * 8);
            }
            int kh = tap / 3, kw = tap % 3;
            const short* abase = sP + ((xr + kh) * 130 + kw + mr) * CPAD + g * 8;
#pragma unroll
            for (int c0 = 0; c0 < NC16; c0++) {
                short8 a[4];
#pragma unroll
                for (int mt = 0; mt < 4; mt++)
                    a[mt] = *(const short8*)(abase + mt * 32 * CPAD + c0 * 16);
#pragma unroll
                for (int mt = 0; mt < 4; mt++) {
                    acc[mt][0] = __builtin_amdgcn_mfma_f32_32x32x16_bf16(a[mt], wbuf[cur][c0][0], acc[mt][0], 0, 0, 0);
                    acc[mt][1] = __builtin_amdgcn_mfma_f32_32x32x16_bf16(a[mt], wbuf[cur][c0][1], acc[mt][1], 0, 0, 0);
                }
            }
        }
    }

    // ---- epilogue ----
    float bv0 = bias[n0 + mr];
    float bv1 = bias[n0 + 32 + mr];
    if (!FUSE) {
        size_t base = ((size_t)b * NX + (x0 + xr)) * NY;
#pragma unroll
        for (int mt = 0; mt < 4; mt++) {
#pragma unroll
            for (int r = 0; r < 16; r++) {
                int y = y0 + mt * 32 + (r & 3) + 8 * (r >> 2) + 4 * g;
                out_bf[(base + y) * C1 + n0 + mr]      = __float2bfloat16(tanh_fast(acc[mt][0][r] + bv0));
                out_bf[(base + y) * C1 + n0 + 32 + mr] = __float2bfloat16(tanh_fast(acc[mt][1][r] + bv1));
            }
        }
    } else {
        float w20 = w2[n0 + mr];
        float w21 = w2[n0 + 32 + mr];
#pragma unroll
        for (int mt = 0; mt < 4; mt++) {
#pragma unroll
            for (int r = 0; r < 16; r++) {
                float v = tanh_fast(acc[mt][0][r] + bv0) * w20
                        + tanh_fast(acc[mt][1][r] + bv1) * w21;
                v += __shfl_xor(v, 1, 64);
                v += __shfl_xor(v, 2, 64);
                v += __shfl_xor(v, 4, 64);
                v += __shfl_xor(v, 8, 64);
                v += __shfl_xor(v, 16, 64);
                if (mr == 0)
                    sred[coh][xr][mt * 32 + (r & 3) + 8 * (r >> 2) + 4 * g] = v;
            }
        }
        __syncthreads();
        {
            int row = tid & 127;
            int xr2 = tid >> 7;
            float r = sred[0][xr2][row] + sred[1][xr2][row] + b2[0];
            out_f[((size_t)b * NX + (x0 + xr2)) * NY + (y0 + row)] = fmaxf(r, 0.f);
        }
    }
}

// ---------------------------------------------------------------------------
extern "C" void kernel_launch(void* const* d_in, const int* in_sizes, int n_in,
                              void* d_out, int out_size, void* d_ws, size_t ws_size,
                              hipStream_t stream) {
    const float* pillars = (const float*)d_in[0];
    const int*   idxs    = (const int*)d_in[1];
    const float* pn_w0   = (const float*)d_in[4];
    const float* pn_b0   = (const float*)d_in[5];
    const float* pn_w1   = (const float*)d_in[6];
    const float* pn_b1   = (const float*)d_in[7];
    const float* cw0     = (const float*)d_in[8];
    const float* cb0     = (const float*)d_in[9];
    const float* cw1     = (const float*)d_in[10];
    const float* cb1     = (const float*)d_in[11];
    const float* cw2     = (const float*)d_in[12];
    const float* cb2     = (const float*)d_in[13];
    float* out = (float*)d_out;

    // workspace layout
    char* ws = (char*)d_ws;
    const size_t IMG_BYTES  = (size_t)B * NX * NY * F * 2;
    const size_t OUT1_BYTES = (size_t)B * NX * NY * C1 * 2;
    const size_t WIN_BYTES  = (size_t)B * NX * NY * 4;
    const size_t PMAX_BYTES = (size_t)B * P * F * 4;
    const size_t WT1_BYTES  = (size_t)9 * C1 * F * 2;
    const size_t WT2_BYTES  = (size_t)9 * C1 * C1 * 2;
    __hip_bfloat16* img  = (__hip_bfloat16*)ws;
    __hip_bfloat16* out1 = (__hip_bfloat16*)(ws + IMG_BYTES);
    int*   winner = (int*)(ws + IMG_BYTES + OUT1_BYTES);
    float* pmax   = (float*)(ws + IMG_BYTES + OUT1_BYTES + WIN_BYTES);
    __hip_bfloat16* wt1 = (__hip_bfloat16*)(ws + IMG_BYTES + OUT1_BYTES + WIN_BYTES + PMAX_BYTES);
    __hip_bfloat16* wt2 = (__hip_bfloat16*)(ws + IMG_BYTES + OUT1_BYTES + WIN_BYTES + PMAX_BYTES + WT1_BYTES);
    __hip_bfloat16* w1t = (__hip_bfloat16*)(ws + IMG_BYTES + OUT1_BYTES + WIN_BYTES + PMAX_BYTES + WT1_BYTES + WT2_BYTES);

    hipMemsetAsync(img, 0, IMG_BYTES, stream);
    hipMemsetAsync(winner, 0xFF, WIN_BYTES, stream);   // -1

    cvt_w_kernel<<<(9 * F * C1 + 255) / 256, 256, 0, stream>>>(cw0, wt1, F);
    cvt_w_kernel<<<(9 * C1 * C1 + 255) / 256, 256, 0, stream>>>(cw1, wt2, C1);
    cvt_w1_kernel<<<(F * F + 255) / 256, 256, 0, stream>>>(pn_w1, w1t);

    pn_mfma_kernel<<<B * P, 128, 0, stream>>>(pillars, pn_w0, pn_b0, w1t, pn_b1, pmax);
    winner_kernel<<<(B * P + 255) / 256, 256, 0, stream>>>(idxs, winner);
    scatter_kernel<<<B * P, 64, 0, stream>>>(idxs, winner, pmax, img);

    conv_mfma<F, false><<<dim3(NX / 2, 2, B), 256, 0, stream>>>(
        img, wt1, cb0, nullptr, nullptr, out1, nullptr);
    conv_mfma<C1, true><<<dim3(NX / 2, 2, B), 256, 0, stream>>>(
        out1, wt2, cb1, cw2, cb2, nullptr, out);
}

// Round 8
// 372.610 us; speedup vs baseline: 6.6251x; 1.0079x over previous
//
#include <hip/hip_runtime.h>
#include <hip/hip_bf16.h>
#include <math.h>

// Problem constants (fixed by setup_inputs)
#define B  4
#define P  5000
#define NPT 100
#define F  64          // pointnet feature dim
#define NX 240
#define NY 240
#define C1 128         // conv1/conv2 out channels

typedef __attribute__((ext_vector_type(8)))  short short8;   // 8 bf16
typedef __attribute__((ext_vector_type(16))) float f32x16;

// tanh via v_exp + v_rcp (rel err ~1e-6; saturates correctly at +-1)
__device__ __forceinline__ float tanh_fast(float x) {
    float e = __expf(2.0f * x);
    float r = __builtin_amdgcn_rcpf(e + 1.0f);
    return __builtin_fmaf(-2.0f, r, 1.0f);
}
__device__ __forceinline__ short bf16_bits(float f) {
    return (short)(__bfloat16_as_ushort(__float2bfloat16(f)));
}

// ---------------------------------------------------------------------------
// PointNet, both layers on MFMA.
// Block = 1 pillar, 128 threads (2 waves); points 100..127 phantoms.
// Layer 1: hi/lo split A (xA, stride 40 shorts: 4-way max bank alias) @
//          precomputed w0p fragments (4 coalesced b128 loads).
// Validity handled by per-wave ballot bitmask; all-valid fast path does a
// pure register max with phantom rows excluded structurally.
// ---------------------------------------------------------------------------
__global__ __launch_bounds__(128) void pn_mfma_kernel(
    const float* __restrict__ pillars,    // [B,P,N,8]
    const short* __restrict__ w0p,        // [4 slots][64 n][8 k] bf16 bits
    const float* __restrict__ b0,         // [64]
    const __hip_bfloat16* __restrict__ w1t, // [64n][64k] bf16
    const float* __restrict__ b1,         // [64]
    float* __restrict__ pmax)             // [B*P,64]
{
    constexpr int HS = F + 8;             // 72 shorts
    constexpr int XS = 40;                // 80B row: bank stride 20 -> max 4-way
    __shared__ short xA[128 * XS];        // 10.0 KB
    __shared__ short hA[128 * HS];        // 18.0 KB
    __shared__ float red[2][F];
    __shared__ unsigned int vb32[4];      // validity bitmask, points 0..127

    int bp = blockIdx.x;
    int n  = threadIdx.x;
    int wave = n >> 6, lane = n & 63;
    int mr = lane & 31;
    int g  = lane >> 5;
    bool live = (n < NPT);

    const float* xp = pillars + ((size_t)bp * NPT + (live ? n : 0)) * 8;
    float4 q0 = *(const float4*)xp;
    float4 q1 = *(const float4*)(xp + 4);
    float x[8] = {q0.x, q0.y, q0.z, q0.w, q1.x, q1.y, q1.z, q1.w};

    float ss = 0.f;
#pragma unroll
    for (int c = 0; c < 8; c++) ss += x[c] * x[c];
    bool valid = live && (ss < 1e12f);

    unsigned long long bal = __ballot(valid);
    if (lane == 0) {
        vb32[wave * 2]     = (unsigned)bal;
        vb32[wave * 2 + 1] = (unsigned)(bal >> 32);
    }

    // hi/lo split of x -> xA row [hi|lo|hi|0]
    short8 xhi, xlo, xz;
#pragma unroll
    for (int c = 0; c < 8; c++) {
        __hip_bfloat16 hb = __float2bfloat16(x[c]);
        float hv = __bfloat162float(hb);
        xhi[c] = (short)__bfloat16_as_ushort(hb);
        xlo[c] = bf16_bits(x[c] - hv);
        xz[c] = 0;
    }
    *(short8*)&xA[n * XS + 0]  = xhi;
    *(short8*)&xA[n * XS + 8]  = xlo;
    *(short8*)&xA[n * XS + 16] = xhi;
    *(short8*)&xA[n * XS + 24] = xz;
    __syncthreads();

    // ---- layer-1 B fragments: 4 coalesced 16B loads ----
    short8 wb[2][2];   // [kk][nt]
#pragma unroll
    for (int kk = 0; kk < 2; kk++)
#pragma unroll
        for (int nt = 0; nt < 2; nt++)
            wb[kk][nt] = *(const short8*)(w0p + ((kk * 2 + g) * 64 + nt * 32 + mr) * 8);

    // ---- layer-1 MFMA ----
    f32x16 hc00 = {0,0,0,0,0,0,0,0,0,0,0,0,0,0,0,0};
    f32x16 hc01 = hc00, hc10 = hc00, hc11 = hc00;
#pragma unroll
    for (int kk = 0; kk < 2; kk++) {
        short8 a0 = *(const short8*)&xA[(wave * 64 + mr) * XS + kk * 16 + g * 8];
        short8 a1 = *(const short8*)&xA[(wave * 64 + 32 + mr) * XS + kk * 16 + g * 8];
        hc00 = __builtin_amdgcn_mfma_f32_32x32x16_bf16(a0, wb[kk][0], hc00, 0, 0, 0);
        hc01 = __builtin_amdgcn_mfma_f32_32x32x16_bf16(a0, wb[kk][1], hc01, 0, 0, 0);
        hc10 = __builtin_amdgcn_mfma_f32_32x32x16_bf16(a1, wb[kk][0], hc10, 0, 0, 0);
        hc11 = __builtin_amdgcn_mfma_f32_32x32x16_bf16(a1, wb[kk][1], hc11, 0, 0, 0);
    }

    // ---- tanh(+b0) -> hA[point][feat] ----
    float b00 = b0[mr];
    float b01 = b0[32 + mr];
#pragma unroll
    for (int mt = 0; mt < 2; mt++) {
#pragma unroll
        for (int r = 0; r < 16; r++) {
            int prow = wave * 64 + mt * 32 + (r & 3) + 8 * (r >> 2) + 4 * g;
            float h0 = (mt == 0) ? hc00[r] : hc10[r];
            float h1 = (mt == 0) ? hc01[r] : hc11[r];
            hA[prow * HS + mr]      = bf16_bits(tanh_fast(h0 + b00));
            hA[prow * HS + 32 + mr] = bf16_bits(tanh_fast(h1 + b01));
        }
    }
    __syncthreads();

    // ---- layer 2 MFMA ----
    short8 bfrag[2][4];
#pragma unroll
    for (int nt = 0; nt < 2; nt++)
#pragma unroll
        for (int c0 = 0; c0 < 4; c0++)
            bfrag[nt][c0] = *(const short8*)((const short*)w1t +
                                (nt * 32 + mr) * F + c0 * 16 + g * 8);

    f32x16 acc00 = {0,0,0,0,0,0,0,0,0,0,0,0,0,0,0,0};
    f32x16 acc01 = acc00, acc10 = acc00, acc11 = acc00;

    const short* arow = &hA[(wave * 64 + mr) * HS + g * 8];
#pragma unroll
    for (int c0 = 0; c0 < 4; c0++) {
        short8 af0 = *(const short8*)(arow + c0 * 16);
        short8 af1 = *(const short8*)(arow + 32 * HS + c0 * 16);
        acc00 = __builtin_amdgcn_mfma_f32_32x32x16_bf16(af0, bfrag[0][c0], acc00, 0, 0, 0);
        acc01 = __builtin_amdgcn_mfma_f32_32x32x16_bf16(af0, bfrag[1][c0], acc01, 0, 0, 0);
        acc10 = __builtin_amdgcn_mfma_f32_32x32x16_bf16(af1, bfrag[0][c0], acc10, 0, 0, 0);
        acc11 = __builtin_amdgcn_mfma_f32_32x32x16_bf16(af1, bfrag[1][c0], acc11, 0, 0, 0);
    }

    // ---- epilogue: masked max over points ----
    float bv0 = b1[mr];
    float bv1 = b1[32 + mr];
    bool allv = ((vb32[0] & vb32[1] & vb32[2]) == 0xFFFFFFFFu) &&
                ((vb32[3] & 0xFu) == 0xFu);
    float mx0 = -INFINITY, mx1 = -INFINITY;

    if (allv) {
        // fast path: every real point valid; phantom rows (>=100) excluded
#pragma unroll
        for (int mt = 0; mt < 2; mt++) {
#pragma unroll
            for (int r = 0; r < 16; r++) {
                bool inc = !(wave == 1 && mt == 1) || (g == 0 && r < 4);
                if (inc) {
                    mx0 = fmaxf(mx0, (mt == 0) ? acc00[r] : acc10[r]);
                    mx1 = fmaxf(mx1, (mt == 0) ? acc01[r] : acc11[r]);
                }
            }
        }
        mx0 += bv0;
        mx1 += bv1;
    } else {
        unsigned wm0 = vb32[wave * 2];
        unsigned wm1 = vb32[wave * 2 + 1];
#pragma unroll
        for (int mt = 0; mt < 2; mt++) {
            unsigned wm = (mt == 0) ? wm0 : wm1;
#pragma unroll
            for (int r = 0; r < 16; r++) {
                int idx = (r & 3) + 8 * (r >> 2) + 4 * g;
                bool inc = !(wave == 1 && mt == 1) || (idx < 4);
                if (inc) {
                    bool vbit = (wm >> idx) & 1;
                    float a0 = (mt == 0) ? acc00[r] : acc10[r];
                    float a1 = (mt == 0) ? acc01[r] : acc11[r];
                    mx0 = fmaxf(mx0, vbit ? (a0 + bv0) : 0.0f);
                    mx1 = fmaxf(mx1, vbit ? (a1 + bv1) : 0.0f);
                }
            }
        }
    }
    mx0 = fmaxf(mx0, __shfl_xor(mx0, 32, 64));
    mx1 = fmaxf(mx1, __shfl_xor(mx1, 32, 64));
    if (lane < 32) { red[wave][mr] = mx0; red[wave][32 + mr] = mx1; }
    __syncthreads();
    if (n < F)
        pmax[(size_t)bp * F + n] = fmaxf(red[0][n], red[1][n]);
}

// ---------------------------------------------------------------------------
// Scatter: numpy last-write-wins via atomicMax(p) + conditional write.
// ---------------------------------------------------------------------------
__global__ __launch_bounds__(256) void winner_kernel(
    const int* __restrict__ idxs, int* __restrict__ winner)
{
    int i = blockIdx.x * 256 + threadIdx.x;
    if (i >= B * P) return;
    int ix = idxs[i * 2], iy = idxs[i * 2 + 1];
    int b = i / P, p = i % P;
    atomicMax(&winner[(b * NX + ix) * NY + iy], p);
}

__global__ __launch_bounds__(64) void scatter_kernel(
    const int* __restrict__ idxs, const int* __restrict__ winner,
    const float* __restrict__ pmax, __hip_bfloat16* __restrict__ img)
{
    int bp = blockIdx.x;
    int f = threadIdx.x;
    int ix = idxs[bp * 2], iy = idxs[bp * 2 + 1];
    int b = bp / P, p = bp % P;
    int cell = (b * NX + ix) * NY + iy;
    if (winner[cell] == p)
        img[(size_t)cell * F + f] = __float2bfloat16(pmax[(size_t)bp * F + f]);
}

// ---------------------------------------------------------------------------
// Weight converts.
// ---------------------------------------------------------------------------
__global__ __launch_bounds__(256) void cvt_w_kernel(
    const float* __restrict__ w, __hip_bfloat16* __restrict__ wt, int cin)
{
    int idx = blockIdx.x * 256 + threadIdx.x;
    int total = 9 * cin * 128;
    if (idx >= total) return;
    int co = idx % 128;
    int rest = idx / 128;
    int ci = rest % cin;
    int t  = rest / cin;
    int c0 = ci >> 4, c16 = ci & 15;
    wt[(((size_t)(t * (cin >> 4) + c0)) * 128 + co) * 16 + c16] = __float2bfloat16(w[idx]);
}

__global__ __launch_bounds__(256) void cvt_w1_kernel(
    const float* __restrict__ w1, __hip_bfloat16* __restrict__ w1t)
{
    int idx = blockIdx.x * 256 + threadIdx.x;
    if (idx >= F * F) return;
    int k = idx >> 6, nn = idx & 63;
    w1t[nn * F + k] = __float2bfloat16(w1[idx]);
}

// w0 [8,64] fp32 -> w0p [4 slots][64 n][8 j] bf16 bits:
// slot 0,1 = w_hi[j][n]; slot 2 = w_lo[j][n]; slot 3 = 0.
__global__ __launch_bounds__(256) void cvt_w0p_kernel(
    const float* __restrict__ w0, short* __restrict__ w0p)
{
    int idx = blockIdx.x * 256 + threadIdx.x;
    if (idx >= 4 * 64 * 8) return;
    int j = idx & 7;
    int nn = (idx >> 3) & 63;
    int s = idx >> 9;
    float wv = w0[j * F + nn];
    __hip_bfloat16 hb = __float2bfloat16(wv);
    short out = 0;
    if (s < 2)      out = (short)__bfloat16_as_ushort(hb);
    else if (s == 2) out = bf16_bits(wv - __bfloat162float(hb));
    w0p[idx] = out;
}

// ---------------------------------------------------------------------------
// MFMA implicit-GEMM 3x3 conv, SAME, Cout=128 (unchanged from R7).
// ---------------------------------------------------------------------------
template<int CIN, bool FUSE>
__global__ __launch_bounds__(256, 2) void conv_mfma(
    const __hip_bfloat16* __restrict__ in,    // [B,240,240,CIN] bf16
    const __hip_bfloat16* __restrict__ wt,    // [9][CIN/16][128][16] bf16
    const float* __restrict__ bias,           // [128]
    const float* __restrict__ w2,             // [128] (FUSE)
    const float* __restrict__ b2,             // [1]   (FUSE)
    __hip_bfloat16* __restrict__ out_bf,
    float* __restrict__ out_f)
{
    constexpr int PASSES = CIN / 64;
    constexpr int CI   = 64;
    constexpr int CPAD = CI + 8;
    constexpr int NC16 = CI / 16;
    constexpr int NC8  = CI / 8;
    constexpr int ROWS = 4 * 130;
    __shared__ short sP[ROWS * CPAD];
    __shared__ float sred[FUSE ? 2 : 1][2][128];

    int tid  = threadIdx.x;
    int wave = tid >> 6;
    int lane = tid & 63;
    int mr = lane & 31;
    int g  = lane >> 5;
    int coh = wave & 1;
    int xr  = wave >> 1;
    int x0 = blockIdx.x * 2;
    int y0 = blockIdx.y * 112;
    int b  = blockIdx.z;
    int n0 = coh * 64;

    const short* wts = (const short*)wt;

    f32x16 acc[4][2];
#pragma unroll
    for (int mt = 0; mt < 4; mt++)
#pragma unroll
        for (int nt = 0; nt < 2; nt++)
            acc[mt][nt] = (f32x16){0,0,0,0,0,0,0,0,0,0,0,0,0,0,0,0};

    short8 wbuf[2][NC16][2];
#pragma unroll
    for (int c0 = 0; c0 < NC16; c0++)
#pragma unroll
        for (int nt = 0; nt < 2; nt++)
            wbuf[0][c0][nt] = *(const short8*)(wts +
                ((0 * (CIN / 16) + c0) * 128 + n0 + nt * 32 + mr) * 16 + g * 8);

#pragma unroll
    for (int p = 0; p < PASSES; p++) {
        if (p) __syncthreads();

#pragma unroll 4
        for (int i = 0; i < 17; i++) {
            int t = tid + i * 256;
            if (t < ROWS * NC8) {
                int c8 = t & (NC8 - 1);
                int r  = t >> 3;
                int dx = r / 130, dy = r - dx * 130;
                int gx = x0 - 1 + dx, gy = y0 - 1 + dy;
                float4 v = make_float4(0.f, 0.f, 0.f, 0.f);
                if (gx >= 0 && gx < NX && gy >= 0 && gy < NY)
                    v = *(const float4*)&in[(((size_t)b * NX + gx) * NY + gy) * CIN + p * CI + c8 * 8];
                *(float4*)&sP[r * CPAD + c8 * 8] = v;
            }
        }
        __syncthreads();

#pragma unroll
        for (int tap = 0; tap < 9; tap++) {
            int s = p * 9 + tap;
            int cur = s & 1;
            if (s + 1 < 9 * PASSES) {
                int sn = s + 1, pn_ = sn / 9, tn = sn % 9;
#pragma unroll
                for (int c0 = 0; c0 < NC16; c0++)
#pragma unroll
                    for (int nt = 0; nt < 2; nt++)
                        wbuf[cur ^ 1][c0][nt] = *(const short8*)(wts +
                            ((tn * (CIN / 16) + pn_ * NC16 + c0) * 128 + n0 + nt * 32 + mr) * 16 + g * 8);
            }
            int kh = tap / 3, kw = tap % 3;
            const short* abase = sP + ((xr + kh) * 130 + kw + mr) * CPAD + g * 8;
#pragma unroll
            for (int c0 = 0; c0 < NC16; c0++) {
                short8 a[4];
#pragma unroll
                for (int mt = 0; mt < 4; mt++)
                    a[mt] = *(const short8*)(abase + mt * 32 * CPAD + c0 * 16);
#pragma unroll
                for (int mt = 0; mt < 4; mt++) {
                    acc[mt][0] = __builtin_amdgcn_mfma_f32_32x32x16_bf16(a[mt], wbuf[cur][c0][0], acc[mt][0], 0, 0, 0);
                    acc[mt][1] = __builtin_amdgcn_mfma_f32_32x32x16_bf16(a[mt], wbuf[cur][c0][1], acc[mt][1], 0, 0, 0);
                }
            }
        }
    }

    float bv0 = bias[n0 + mr];
    float bv1 = bias[n0 + 32 + mr];
    if (!FUSE) {
        size_t base = ((size_t)b * NX + (x0 + xr)) * NY;
#pragma unroll
        for (int mt = 0; mt < 4; mt++) {
#pragma unroll
            for (int r = 0; r < 16; r++) {
                int y = y0 + mt * 32 + (r & 3) + 8 * (r >> 2) + 4 * g;
                out_bf[(base + y) * C1 + n0 + mr]      = __float2bfloat16(tanh_fast(acc[mt][0][r] + bv0));
                out_bf[(base + y) * C1 + n0 + 32 + mr] = __float2bfloat16(tanh_fast(acc[mt][1][r] + bv1));
            }
        }
    } else {
        float w20 = w2[n0 + mr];
        float w21 = w2[n0 + 32 + mr];
#pragma unroll
        for (int mt = 0; mt < 4; mt++) {
#pragma unroll
            for (int r = 0; r < 16; r++) {
                float v = tanh_fast(acc[mt][0][r] + bv0) * w20
                        + tanh_fast(acc[mt][1][r] + bv1) * w21;
                v += __shfl_xor(v, 1, 64);
                v += __shfl_xor(v, 2, 64);
                v += __shfl_xor(v, 4, 64);
                v += __shfl_xor(v, 8, 64);
                v += __shfl_xor(v, 16, 64);
                if (mr == 0)
                    sred[coh][xr][mt * 32 + (r & 3) + 8 * (r >> 2) + 4 * g] = v;
            }
        }
        __syncthreads();
        {
            int row = tid & 127;
            int xr2 = tid >> 7;
            float r = sred[0][xr2][row] + sred[1][xr2][row] + b2[0];
            out_f[((size_t)b * NX + (x0 + xr2)) * NY + (y0 + row)] = fmaxf(r, 0.f);
        }
    }
}

// ---------------------------------------------------------------------------
extern "C" void kernel_launch(void* const* d_in, const int* in_sizes, int n_in,
                              void* d_out, int out_size, void* d_ws, size_t ws_size,
                              hipStream_t stream) {
    const float* pillars = (const float*)d_in[0];
    const int*   idxs    = (const int*)d_in[1];
    const float* pn_w0   = (const float*)d_in[4];
    const float* pn_b0   = (const float*)d_in[5];
    const float* pn_w1   = (const float*)d_in[6];
    const float* pn_b1   = (const float*)d_in[7];
    const float* cw0     = (const float*)d_in[8];
    const float* cb0     = (const float*)d_in[9];
    const float* cw1     = (const float*)d_in[10];
    const float* cb1     = (const float*)d_in[11];
    const float* cw2     = (const float*)d_in[12];
    const float* cb2     = (const float*)d_in[13];
    float* out = (float*)d_out;

    // workspace layout
    char* ws = (char*)d_ws;
    const size_t IMG_BYTES  = (size_t)B * NX * NY * F * 2;
    const size_t OUT1_BYTES = (size_t)B * NX * NY * C1 * 2;
    const size_t WIN_BYTES  = (size_t)B * NX * NY * 4;
    const size_t PMAX_BYTES = (size_t)B * P * F * 4;
    const size_t WT1_BYTES  = (size_t)9 * C1 * F * 2;
    const size_t WT2_BYTES  = (size_t)9 * C1 * C1 * 2;
    const size_t W1T_BYTES  = (size_t)F * F * 2;
    __hip_bfloat16* img  = (__hip_bfloat16*)ws;
    __hip_bfloat16* out1 = (__hip_bfloat16*)(ws + IMG_BYTES);
    int*   winner = (int*)(ws + IMG_BYTES + OUT1_BYTES);
    float* pmax   = (float*)(ws + IMG_BYTES + OUT1_BYTES + WIN_BYTES);
    __hip_bfloat16* wt1 = (__hip_bfloat16*)(ws + IMG_BYTES + OUT1_BYTES + WIN_BYTES + PMAX_BYTES);
    __hip_bfloat16* wt2 = (__hip_bfloat16*)(ws + IMG_BYTES + OUT1_BYTES + WIN_BYTES + PMAX_BYTES + WT1_BYTES);
    __hip_bfloat16* w1t = (__hip_bfloat16*)(ws + IMG_BYTES + OUT1_BYTES + WIN_BYTES + PMAX_BYTES + WT1_BYTES + WT2_BYTES);
    short* w0p = (short*)(ws + IMG_BYTES + OUT1_BYTES + WIN_BYTES + PMAX_BYTES + WT1_BYTES + WT2_BYTES + W1T_BYTES);

    hipMemsetAsync(img, 0, IMG_BYTES, stream);
    hipMemsetAsync(winner, 0xFF, WIN_BYTES, stream);   // -1

    cvt_w_kernel<<<(9 * F * C1 + 255) / 256, 256, 0, stream>>>(cw0, wt1, F);
    cvt_w_kernel<<<(9 * C1 * C1 + 255) / 256, 256, 0, stream>>>(cw1, wt2, C1);
    cvt_w1_kernel<<<(F * F + 255) / 256, 256, 0, stream>>>(pn_w1, w1t);
    cvt_w0p_kernel<<<(4 * 64 * 8 + 255) / 256, 256, 0, stream>>>(pn_w0, w0p);

    pn_mfma_kernel<<<B * P, 128, 0, stream>>>(pillars, w0p, pn_b0, w1t, pn_b1, pmax);
    winner_kernel<<<(B * P + 255) / 256, 256, 0, stream>>>(idxs, winner);
    scatter_kernel<<<B * P, 64, 0, stream>>>(idxs, winner, pmax, img);

    conv_mfma<F, false><<<dim3(NX / 2, 2, B), 256, 0, stream>>>(
        img, wt1, cb0, nullptr, nullptr, out1, nullptr);
    conv_mfma<C1, true><<<dim3(NX / 2, 2, B), 256, 0, stream>>>(
        out1, wt2, cb1, cw2, cb2, nullptr, out);
}